// Round 1
// baseline (4117.910 us; speedup 1.0000x reference)
//
#include <hip/hip_runtime.h>
#include <hip/hip_bf16.h>
#include <math.h>

// Problem constants
#define TT   2048      // T
#define DDIM 512       // D
#define NEGI -1e30f

enum { EPI_BIAS = 0, EPI_PE = 1, EPI_RES = 2, EPI_GELU = 3 };

// ---------------------------------------------------------------------------
// Generic fp32 tiled GEMM: C[M,N] = A[M,K] @ B[K,N] + bias  (+epilogue)
// BM=128, BN=64, BK=16, 256 threads, 8x4 per thread.
// EPI_PE:  += sinusoidal PE(t=row%T, col)
// EPI_RES: += R[row,col]   (R may alias C; same thread reads-then-writes)
// EPI_GELU: exact gelu via erff
// ---------------------------------------------------------------------------
template<int EPI>
__global__ __launch_bounds__(256)
void k_gemm(const float* __restrict__ A, const float* __restrict__ Bm,
            const float* __restrict__ bias, const float* __restrict__ R,
            float* __restrict__ C, int M, int N, int K)
{
    __shared__ float As[16][132];   // transposed A tile: As[k][m], pad->132
    __shared__ float Bs[16][64];
    const int tid = threadIdx.x;
    const int tx = tid & 15, ty = tid >> 4;
    const int row0 = blockIdx.y * 128, col0 = blockIdx.x * 64;

    float acc[8][4];
#pragma unroll
    for (int i = 0; i < 8; ++i)
#pragma unroll
        for (int j = 0; j < 4; ++j) acc[i][j] = 0.f;

    for (int kt = 0; kt < K; kt += 16) {
        // A tile: 128x16 = 512 float4, 2 per thread (coalesced along K)
#pragma unroll
        for (int e = 0; e < 2; ++e) {
            int f  = tid + e * 256;
            int m  = f >> 2;
            int k4 = (f & 3) << 2;
            const float4 v = *(const float4*)&A[(size_t)(row0 + m) * K + kt + k4];
            As[k4 + 0][m] = v.x; As[k4 + 1][m] = v.y;
            As[k4 + 2][m] = v.z; As[k4 + 3][m] = v.w;
        }
        // B tile: 16x64 = 256 float4, 1 per thread
        {
            int k  = tid >> 4;
            int n4 = (tid & 15) << 2;
            *(float4*)&Bs[k][n4] = *(const float4*)&Bm[(size_t)(kt + k) * N + col0 + n4];
        }
        __syncthreads();
#pragma unroll
        for (int kk = 0; kk < 16; ++kk) {
            float4 a0 = *(const float4*)&As[kk][ty * 8];
            float4 a1 = *(const float4*)&As[kk][ty * 8 + 4];
            float4 b0 = *(const float4*)&Bs[kk][tx * 4];
            float a[8] = {a0.x, a0.y, a0.z, a0.w, a1.x, a1.y, a1.z, a1.w};
            float b[4] = {b0.x, b0.y, b0.z, b0.w};
#pragma unroll
            for (int i = 0; i < 8; ++i)
#pragma unroll
                for (int j = 0; j < 4; ++j) acc[i][j] = fmaf(a[i], b[j], acc[i][j]);
        }
        __syncthreads();
    }

    // epilogue
#pragma unroll
    for (int i = 0; i < 8; ++i) {
        const int row  = row0 + ty * 8 + i;
        const int colb = col0 + tx * 4;
        float4 out;
        float* po = &out.x;
#pragma unroll
        for (int j = 0; j < 4; ++j) {
            const int col = colb + j;
            float v = acc[i][j] + bias[col];
            if constexpr (EPI == EPI_PE) {
                const int t  = row & (TT - 1);          // row = b*T + t
                const int i2 = col & ~1;
                // div_i = exp(-(2i) * ln(10000)/512)
                const float freq = __expf(-(float)i2 * 0.017988946039015984f);
                const float ang  = (float)t * freq;
                v += (col & 1) ? cosf(ang) : sinf(ang);
            }
            if constexpr (EPI == EPI_RES) {
                v += R[(size_t)row * N + col];
            }
            if constexpr (EPI == EPI_GELU) {
                v = 0.5f * v * (1.f + erff(v * 0.7071067811865475f));
            }
            po[j] = v;
        }
        *(float4*)&C[(size_t)row * N + colb] = out;
    }
}

// ---------------------------------------------------------------------------
// LayerNorm over D=512, one wave per row, 8 elems/lane, eps=1e-5
// ---------------------------------------------------------------------------
__global__ __launch_bounds__(256)
void k_ln(const float* __restrict__ X, const float* __restrict__ g,
          const float* __restrict__ b, float* __restrict__ Y)
{
    const int lane = threadIdx.x & 63;
    const int row  = blockIdx.x * 4 + (threadIdx.x >> 6);
    const float* x = X + (size_t)row * DDIM + lane * 8;

    float4 v0 = *(const float4*)x;
    float4 v1 = *(const float4*)(x + 4);
    float vals[8] = {v0.x, v0.y, v0.z, v0.w, v1.x, v1.y, v1.z, v1.w};

    float s = 0.f;
#pragma unroll
    for (int i = 0; i < 8; ++i) s += vals[i];
#pragma unroll
    for (int off = 32; off >= 1; off >>= 1) s += __shfl_xor(s, off);
    const float mu = s * (1.f / DDIM);

    float sq = 0.f;
#pragma unroll
    for (int i = 0; i < 8; ++i) { float d = vals[i] - mu; sq += d * d; }
#pragma unroll
    for (int off = 32; off >= 1; off >>= 1) sq += __shfl_xor(sq, off);
    const float rs = rsqrtf(sq * (1.f / DDIM) + 1e-5f);

    const float* gp = g + lane * 8;
    const float* bp = b + lane * 8;
    float4 g0 = *(const float4*)gp, g1 = *(const float4*)(gp + 4);
    float4 b0 = *(const float4*)bp, b1 = *(const float4*)(bp + 4);
    float ga[8] = {g0.x, g0.y, g0.z, g0.w, g1.x, g1.y, g1.z, g1.w};
    float bb[8] = {b0.x, b0.y, b0.z, b0.w, b1.x, b1.y, b1.z, b1.w};

    float4 o0, o1;
    float* p0 = &o0.x; float* p1 = &o1.x;
#pragma unroll
    for (int i = 0; i < 4; ++i) p0[i] = (vals[i] - mu) * rs * ga[i] + bb[i];
#pragma unroll
    for (int i = 0; i < 4; ++i) p1[i] = (vals[4 + i] - mu) * rs * ga[4 + i] + bb[4 + i];
    float* yp = Y + (size_t)row * DDIM + lane * 8;
    *(float4*)yp       = o0;
    *(float4*)(yp + 4) = o1;
}

// ---------------------------------------------------------------------------
// Causal flash attention, fp32. The reference's ALiBi bias is identically 0
// in the visible (j<=i) region, so this is plain causal attention, scale=1/8.
// qkv: [B*T, 1536] (q|k|v each 512 wide, head h at h*64).
// Grid: (T/64, B*H). 256 threads: thread = (r, c) = q-row r in tile, dim
// quarter c (16 dims). 4-lane shfl_xor reduces the QK dot.
// ---------------------------------------------------------------------------
__global__ __launch_bounds__(256)
void k_attn(const float* __restrict__ qkv, float* __restrict__ att)
{
    __shared__ float Ks[64][68];
    __shared__ float Vs[64][68];
    const int qblk = blockIdx.x;
    const int bh   = blockIdx.y;
    const int b    = bh >> 3, h = bh & 7;
    const int tid  = threadIdx.x;
    const int r    = tid >> 2, c = tid & 3;
    const int qg   = qblk * 64 + r;

    const float* qrow = qkv + (size_t)(b * TT + qg) * 1536 + h * 64 + c * 16;
    float q[16];
    {
        float4 q0 = *(const float4*)qrow;
        float4 q1 = *(const float4*)(qrow + 4);
        float4 q2 = *(const float4*)(qrow + 8);
        float4 q3 = *(const float4*)(qrow + 12);
        const float sc = 0.125f;   // 1/sqrt(64)
        q[0]=q0.x*sc; q[1]=q0.y*sc; q[2]=q0.z*sc; q[3]=q0.w*sc;
        q[4]=q1.x*sc; q[5]=q1.y*sc; q[6]=q1.z*sc; q[7]=q1.w*sc;
        q[8]=q2.x*sc; q[9]=q2.y*sc; q[10]=q2.z*sc; q[11]=q2.w*sc;
        q[12]=q3.x*sc; q[13]=q3.y*sc; q[14]=q3.z*sc; q[15]=q3.w*sc;
    }

    float o[16];
#pragma unroll
    for (int i = 0; i < 16; ++i) o[i] = 0.f;
    float m = NEGI, l = 0.f;

    for (int kb = 0; kb <= qblk; ++kb) {
        __syncthreads();   // previous-tile LDS reads done before overwrite
        const float* base = qkv + (size_t)(b * TT + kb * 64) * 1536 + h * 64;
#pragma unroll
        for (int e = 0; e < 4; ++e) {
            int f  = tid + e * 256;
            int kr = f >> 4;
            int kc = (f & 15) << 2;
            const float* src = base + (size_t)kr * 1536 + kc;
            *(float4*)&Ks[kr][kc] = *(const float4*)(src + 512);
            *(float4*)&Vs[kr][kc] = *(const float4*)(src + 1024);
        }
        __syncthreads();

        const bool diag = (kb == qblk);
        float s[64];
#pragma unroll
        for (int j = 0; j < 64; ++j) {
            const float* kp = &Ks[j][c * 16];
            float4 k0 = *(const float4*)kp;
            float4 k1 = *(const float4*)(kp + 4);
            float4 k2 = *(const float4*)(kp + 8);
            float4 k3 = *(const float4*)(kp + 12);
            float d;
            d  = q[0]*k0.x  + q[1]*k0.y  + q[2]*k0.z  + q[3]*k0.w;
            d += q[4]*k1.x  + q[5]*k1.y  + q[6]*k1.z  + q[7]*k1.w;
            d += q[8]*k2.x  + q[9]*k2.y  + q[10]*k2.z + q[11]*k2.w;
            d += q[12]*k3.x + q[13]*k3.y + q[14]*k3.z + q[15]*k3.w;
            d += __shfl_xor(d, 1);
            d += __shfl_xor(d, 2);
            s[j] = (diag && j > r) ? NEGI : d;
        }

        float tm = s[0];
#pragma unroll
        for (int j = 1; j < 64; ++j) tm = fmaxf(tm, s[j]);
        const float mn    = fmaxf(m, tm);
        const float alpha = __expf(m - mn);
        m = mn;

        float ps = 0.f;
#pragma unroll
        for (int j = 0; j < 64; ++j) { s[j] = __expf(s[j] - mn); ps += s[j]; }
        l = l * alpha + ps;

#pragma unroll
        for (int i = 0; i < 16; ++i) o[i] *= alpha;
#pragma unroll
        for (int j = 0; j < 64; ++j) {
            const float* vp = &Vs[j][c * 16];
            float4 v0 = *(const float4*)vp;
            float4 v1 = *(const float4*)(vp + 4);
            float4 v2 = *(const float4*)(vp + 8);
            float4 v3 = *(const float4*)(vp + 12);
            const float p = s[j];
            o[0]  += p * v0.x; o[1]  += p * v0.y; o[2]  += p * v0.z; o[3]  += p * v0.w;
            o[4]  += p * v1.x; o[5]  += p * v1.y; o[6]  += p * v1.z; o[7]  += p * v1.w;
            o[8]  += p * v2.x; o[9]  += p * v2.y; o[10] += p * v2.z; o[11] += p * v2.w;
            o[12] += p * v3.x; o[13] += p * v3.y; o[14] += p * v3.z; o[15] += p * v3.w;
        }
    }

    const float inv = 1.f / l;
    float* op = att + (size_t)(b * TT + qg) * DDIM + h * 64 + c * 16;
    float4 r0 = make_float4(o[0]*inv,  o[1]*inv,  o[2]*inv,  o[3]*inv);
    float4 r1 = make_float4(o[4]*inv,  o[5]*inv,  o[6]*inv,  o[7]*inv);
    float4 r2 = make_float4(o[8]*inv,  o[9]*inv,  o[10]*inv, o[11]*inv);
    float4 r3 = make_float4(o[12]*inv, o[13]*inv, o[14]*inv, o[15]*inv);
    *(float4*)op        = r0;
    *(float4*)(op + 4)  = r1;
    *(float4*)(op + 8)  = r2;
    *(float4*)(op + 12) = r3;
}

// ---------------------------------------------------------------------------
extern "C" void kernel_launch(void* const* d_in, const int* in_sizes, int n_in,
                              void* d_out, int out_size, void* d_ws, size_t ws_size,
                              hipStream_t stream)
{
    const float* x    = (const float*)d_in[0];
    const float* Win  = (const float*)d_in[1];
    const float* bin_ = (const float*)d_in[2];
    const float* Wqkv = (const float*)d_in[3];
    const float* bqkv = (const float*)d_in[4];
    const float* Wo   = (const float*)d_in[5];
    const float* bo   = (const float*)d_in[6];
    const float* ln1g = (const float*)d_in[7];
    const float* ln1b = (const float*)d_in[8];
    const float* Wf1  = (const float*)d_in[9];
    const float* bf1  = (const float*)d_in[10];
    const float* Wf2  = (const float*)d_in[11];
    const float* bf2  = (const float*)d_in[12];
    const float* ln2g = (const float*)d_in[13];
    const float* ln2b = (const float*)d_in[14];
    const float* lnfg = (const float*)d_in[15];
    const float* lnfb = (const float*)d_in[16];
    const float* Wout = (const float*)d_in[17];
    const float* bout = (const float*)d_in[18];
    float* out = (float*)d_out;

    const int M = 2 * TT;                 // 4096 rows
    float* h   = (float*)d_ws;            // [4096,512]   residual stream
    float* y   = h + (size_t)M * 512;     // [4096,512]   LN out / attn out
    float* big = y + (size_t)M * 512;     // [4096,2048]  qkv (1536) / ff1 (2048)

    dim3 blk(256);

    // input projection + sinusoidal PE
    k_gemm<EPI_PE><<<dim3(8, 32), blk, 0, stream>>>(x, Win, bin_, nullptr, h, M, 512, 128);

    for (int l = 0; l < 4; ++l) {
        k_ln<<<dim3(M / 4), blk, 0, stream>>>(h, ln1g + l * 512, ln1b + l * 512, y);
        k_gemm<EPI_BIAS><<<dim3(24, 32), blk, 0, stream>>>(
            y, Wqkv + (size_t)l * 512 * 1536, bqkv + l * 1536, nullptr, big, M, 1536, 512);
        k_attn<<<dim3(32, 16), blk, 0, stream>>>(big, y);
        k_gemm<EPI_RES><<<dim3(8, 32), blk, 0, stream>>>(
            y, Wo + (size_t)l * 512 * 512, bo + l * 512, h, h, M, 512, 512);
        k_ln<<<dim3(M / 4), blk, 0, stream>>>(h, ln2g + l * 512, ln2b + l * 512, y);
        k_gemm<EPI_GELU><<<dim3(32, 32), blk, 0, stream>>>(
            y, Wf1 + (size_t)l * 512 * 2048, bf1 + l * 2048, nullptr, big, M, 2048, 512);
        k_gemm<EPI_RES><<<dim3(8, 32), blk, 0, stream>>>(
            big, Wf2 + (size_t)l * 2048 * 512, bf2 + l * 512, h, h, M, 512, 2048);
    }

    k_ln<<<dim3(M / 4), blk, 0, stream>>>(h, lnfg, lnfb, y);
    k_gemm<EPI_BIAS><<<dim3(2, 32), blk, 0, stream>>>(y, Wout, bout, nullptr, out, M, 128, 512);
}

// Round 2
// 883.096 us; speedup vs baseline: 4.6630x; 4.6630x over previous
//
#include <hip/hip_runtime.h>
#include <math.h>
#include <type_traits>
#include <utility>

#define TT 2048
typedef unsigned short u16;
typedef unsigned int u32;
typedef float f32x4 __attribute__((ext_vector_type(4)));
typedef short s16x8 __attribute__((ext_vector_type(8)));
typedef __bf16 bf16x8 __attribute__((ext_vector_type(8)));

enum { EPI_PE = 0, EPI_QKV = 1, EPI_RES = 2, EPI_GELU = 3, EPI_OUTF = 4 };

// ---- MFMA wrapper: handles either builtin signature (v8i16 or v8bf16) ----
template<typename V, typename = void> struct mfma_takes : std::false_type {};
template<typename V> struct mfma_takes<V, std::void_t<decltype(
    __builtin_amdgcn_mfma_f32_16x16x32_bf16(std::declval<V>(), std::declval<V>(),
                                            std::declval<f32x4>(), 0, 0, 0))>>
    : std::true_type {};

template<typename VA>
__device__ __forceinline__ f32x4 MFMA_t(VA a, VA b, f32x4 c) {
    if constexpr (mfma_takes<VA>::value) {
        return __builtin_amdgcn_mfma_f32_16x16x32_bf16(a, b, c, 0, 0, 0);
    } else {
        return __builtin_amdgcn_mfma_f32_16x16x32_bf16(
            __builtin_bit_cast(bf16x8, a), __builtin_bit_cast(bf16x8, b), c, 0, 0, 0);
    }
}

// fp32 -> bf16 RNE
__device__ __forceinline__ u16 f2b(float f) {
    u32 u = __float_as_uint(f);
    return (u16)((u + 0x7FFFu + ((u >> 16) & 1u)) >> 16);
}

// async global->LDS, 16B per lane; LDS dest = uniform base + lane*16
__device__ __forceinline__ void gload16(const void* g, void* lds_base, int lds_byte_off) {
    __builtin_amdgcn_global_load_lds(
        (const __attribute__((address_space(1))) void*)g,
        (__attribute__((address_space(3))) void*)((char*)lds_base + lds_byte_off),
        16, 0, 0);
}

// ---------------------------------------------------------------------------
// bf16 MFMA GEMM: C[M,N] = A[M,K](bf16 row-major) @ Bt[N,K]^T (bf16) + bias
// 128x128 tile, BK=32, 4 waves (2x2), each wave 64x64 = 4x4 frags of 16x16.
// LDS tiles [128 rows][32 k], 16B chunks swizzled: chunk kg stored at
// kg ^ ((row>>1)&3)  (bank-conflict-free frag reads, involution).
// ---------------------------------------------------------------------------
template<int EPI>
__global__ __launch_bounds__(256)
void k_gemm_mfma(const u16* __restrict__ A, const u16* __restrict__ Bt,
                 const float* __restrict__ bias, const float* __restrict__ Rf,
                 void* __restrict__ Cout, int M, int N, int K)
{
    __shared__ __attribute__((aligned(16))) u16 As[128 * 32];
    __shared__ __attribute__((aligned(16))) u16 Bs[128 * 32];
    const int tid = threadIdx.x;
    const int l = tid & 63, wv = tid >> 6;
    const int l15 = l & 15, lg = l >> 4;
    const int wr = wv >> 1, wc = wv & 1;
    const int row0 = blockIdx.y * 128, col0 = blockIdx.x * 128;

    f32x4 acc[4][4];
#pragma unroll
    for (int m = 0; m < 4; ++m)
#pragma unroll
        for (int n = 0; n < 4; ++n) acc[m][n] = (f32x4){0.f, 0.f, 0.f, 0.f};

    for (int kt = 0; kt < K; kt += 32) {
#pragma unroll
        for (int i = 0; i < 2; ++i) {
            const int u = i * 256 + wv * 64 + l;     // 16B-chunk index, 512 total
            const int ar = u >> 2, ac = u & 3;       // row, stored-chunk
            const int sc = (ac ^ ((ar >> 1) & 3)) << 3;  // source logical chunk *8 elems
            const int off = __builtin_amdgcn_readfirstlane((i * 256 + wv * 64) * 16);
            gload16(A  + (size_t)(row0 + ar) * K + kt + sc, As, off);
            gload16(Bt + (size_t)(col0 + ar) * K + kt + sc, Bs, off);
        }
        __syncthreads();
        s16x8 af[4], bf[4];
#pragma unroll
        for (int m = 0; m < 4; ++m) {
            const int r = wr * 64 + m * 16 + l15;
            af[m] = *(const s16x8*)(As + r * 32 + ((lg ^ ((r >> 1) & 3)) << 3));
        }
#pragma unroll
        for (int n = 0; n < 4; ++n) {
            const int r = wc * 64 + n * 16 + l15;
            bf[n] = *(const s16x8*)(Bs + r * 32 + ((lg ^ ((r >> 1) & 3)) << 3));
        }
#pragma unroll
        for (int m = 0; m < 4; ++m)
#pragma unroll
            for (int n = 0; n < 4; ++n) acc[m][n] = MFMA_t(af[m], bf[n], acc[m][n]);
        __syncthreads();
    }

#pragma unroll
    for (int m = 0; m < 4; ++m)
#pragma unroll
        for (int rg = 0; rg < 4; ++rg) {
            const int row = row0 + wr * 64 + m * 16 + lg * 4 + rg;
#pragma unroll
            for (int n = 0; n < 4; ++n) {
                const int col = col0 + wc * 64 + n * 16 + l15;
                float v = acc[m][n][rg] + bias[col];
                const size_t idx = (size_t)row * N + col;
                if constexpr (EPI == EPI_PE) {
                    const int t = row & (TT - 1);
                    const float freq = __expf(-(float)(col & ~1) * 0.017988946039015984f);
                    const float ang = (float)t * freq;
                    v += (col & 1) ? cosf(ang) : sinf(ang);
                    ((float*)Cout)[idx] = v;
                } else if constexpr (EPI == EPI_QKV) {
                    ((u16*)Cout)[idx] = f2b(v);
                } else if constexpr (EPI == EPI_GELU) {
                    v = 0.5f * v * (1.f + erff(v * 0.7071067811865475f));
                    ((u16*)Cout)[idx] = f2b(v);
                } else if constexpr (EPI == EPI_RES) {
                    ((float*)Cout)[idx] = Rf[idx] + v;
                } else {
                    ((float*)Cout)[idx] = v;
                }
            }
        }
}

// ---------------------------------------------------------------------------
// LayerNorm D=512: h(fp32) -> y(bf16). One wave per row.
// ---------------------------------------------------------------------------
__global__ __launch_bounds__(256)
void k_ln(const float* __restrict__ X, const float* __restrict__ g,
          const float* __restrict__ b, u16* __restrict__ Y)
{
    const int lane = threadIdx.x & 63;
    const int row = blockIdx.x * 4 + (threadIdx.x >> 6);
    const float* x = X + (size_t)row * 512 + lane * 8;

    float4 v0 = *(const float4*)x;
    float4 v1 = *(const float4*)(x + 4);
    float vals[8] = {v0.x, v0.y, v0.z, v0.w, v1.x, v1.y, v1.z, v1.w};

    float s = 0.f;
#pragma unroll
    for (int i = 0; i < 8; ++i) s += vals[i];
#pragma unroll
    for (int off = 32; off >= 1; off >>= 1) s += __shfl_xor(s, off);
    const float mu = s * (1.f / 512.f);

    float sq = 0.f;
#pragma unroll
    for (int i = 0; i < 8; ++i) { float d = vals[i] - mu; sq += d * d; }
#pragma unroll
    for (int off = 32; off >= 1; off >>= 1) sq += __shfl_xor(sq, off);
    const float rs = rsqrtf(sq * (1.f / 512.f) + 1e-5f);

    const float* gp = g + lane * 8;
    const float* bp = b + lane * 8;
    float4 g0 = *(const float4*)gp, g1 = *(const float4*)(gp + 4);
    float4 b0 = *(const float4*)bp, b1 = *(const float4*)(bp + 4);
    float ga[8] = {g0.x, g0.y, g0.z, g0.w, g1.x, g1.y, g1.z, g1.w};
    float bb[8] = {b0.x, b0.y, b0.z, b0.w, b1.x, b1.y, b1.z, b1.w};

    u32 pk[4];
#pragma unroll
    for (int i = 0; i < 4; ++i) {
        float a0 = (vals[2 * i]     - mu) * rs * ga[2 * i]     + bb[2 * i];
        float a1 = (vals[2 * i + 1] - mu) * rs * ga[2 * i + 1] + bb[2 * i + 1];
        pk[i] = (u32)f2b(a0) | ((u32)f2b(a1) << 16);
    }
    *(uint4*)(Y + (size_t)row * 512 + lane * 8) = make_uint4(pk[0], pk[1], pk[2], pk[3]);
}

// ---------------------------------------------------------------------------
// Causal MFMA flash attention (ALiBi bias == 0 in visible region).
// Grid (32 qblks, 16 bh). 4 waves, wave w owns q-rows qblk*64+w*16..+15.
// K staged [kv][64] swizzled; V^T staged [d][kv] swizzled from global Vt.
// P round-trips through wave-private swizzled LDS to reach A-frag layout.
// ---------------------------------------------------------------------------
__global__ __launch_bounds__(256)
void k_attn(const u16* __restrict__ qkv, const u16* __restrict__ Vt, u16* __restrict__ y)
{
    __shared__ __attribute__((aligned(16))) u16 Ks[64 * 64];
    __shared__ __attribute__((aligned(16))) u16 Vs[64 * 64];
    __shared__ __attribute__((aligned(16))) u16 Ps[4][16 * 64];
    const int tid = threadIdx.x;
    const int l = tid & 63, w = tid >> 6;
    const int l15 = l & 15, lg = l >> 4;
    const int qblk = blockIdx.x, bh = blockIdx.y;
    const int b = bh >> 3, hh = bh & 7;

    const int qrow = qblk * 64 + w * 16 + l15;
    const u16* qptr = qkv + (size_t)(b * TT + qrow) * 1536 + hh * 64 + lg * 8;
    const s16x8 qa0 = *(const s16x8*)qptr;
    const s16x8 qa1 = *(const s16x8*)(qptr + 32);

    f32x4 o[4];
#pragma unroll
    for (int nd = 0; nd < 4; ++nd) o[nd] = (f32x4){0.f, 0.f, 0.f, 0.f};
    float mreg[4] = {-1e30f, -1e30f, -1e30f, -1e30f};
    float lsum[4] = {0.f, 0.f, 0.f, 0.f};

    for (int kb = 0; kb <= qblk; ++kb) {
#pragma unroll
        for (int i = 0; i < 2; ++i) {
            const int u = i * 256 + w * 64 + l;
            const int kv = u >> 3, c = u & 7;
            const int sc = (c ^ (kv & 7)) << 3;
            const int off = __builtin_amdgcn_readfirstlane((i * 256 + w * 64) * 16);
            gload16(qkv + (size_t)(b * TT + kb * 64 + kv) * 1536 + 512 + hh * 64 + sc, Ks, off);
            gload16(Vt + (size_t)(bh * 64 + kv) * 2048 + kb * 64 + sc, Vs, off);
        }
        __syncthreads();

        // S = Q K^T (scaled later)
        f32x4 sf[4];
#pragma unroll
        for (int nb = 0; nb < 4; ++nb) {
            const int kv = nb * 16 + l15;
            const u16* kr = Ks + kv * 64;
            s16x8 k0 = *(const s16x8*)(kr + ((lg ^ (kv & 7)) << 3));
            s16x8 k1 = *(const s16x8*)(kr + (((lg + 4) ^ (kv & 7)) << 3));
            f32x4 z = (f32x4){0.f, 0.f, 0.f, 0.f};
            sf[nb] = MFMA_t(qa1, k1, MFMA_t(qa0, k0, z));
        }

        float p[4][4]; // [nb][rg]
        const bool diag = (kb == qblk);
#pragma unroll
        for (int nb = 0; nb < 4; ++nb)
#pragma unroll
            for (int rg = 0; rg < 4; ++rg) {
                float v = sf[nb][rg] * 0.125f;
                if (diag && (nb * 16 + l15) > (w * 16 + lg * 4 + rg)) v = -1e30f;
                p[nb][rg] = v;
            }

#pragma unroll
        for (int rg = 0; rg < 4; ++rg) {
            float rm = fmaxf(fmaxf(p[0][rg], p[1][rg]), fmaxf(p[2][rg], p[3][rg]));
            rm = fmaxf(rm, __shfl_xor(rm, 1));
            rm = fmaxf(rm, __shfl_xor(rm, 2));
            rm = fmaxf(rm, __shfl_xor(rm, 4));
            rm = fmaxf(rm, __shfl_xor(rm, 8));
            const float mn = fmaxf(mreg[rg], rm);
            const float alpha = __expf(mreg[rg] - mn);
            mreg[rg] = mn;
            float ps = 0.f;
#pragma unroll
            for (int nb = 0; nb < 4; ++nb) {
                float e = __expf(p[nb][rg] - mn);
                p[nb][rg] = e;
                ps += e;
            }
            ps += __shfl_xor(ps, 1); ps += __shfl_xor(ps, 2);
            ps += __shfl_xor(ps, 4); ps += __shfl_xor(ps, 8);
            lsum[rg] = lsum[rg] * alpha + ps;
#pragma unroll
            for (int nd = 0; nd < 4; ++nd) o[nd][rg] *= alpha;
        }

        // P -> wave-private LDS in A-frag-friendly swizzled [r][kv] layout
        u16* pw = Ps[w];
#pragma unroll
        for (int nb = 0; nb < 4; ++nb)
#pragma unroll
            for (int rg = 0; rg < 4; ++rg) {
                const int col = nb * 16 + l15, r = lg * 4 + rg;
                const int pos = (col >> 3) ^ (r & 7);
                pw[r * 64 + pos * 8 + (col & 7)] = f2b(p[nb][rg]);
            }
        asm volatile("s_waitcnt lgkmcnt(0)" ::: "memory");

        // O += P V
        const int rr = l15;
        s16x8 pa0 = *(const s16x8*)(pw + rr * 64 + ((lg ^ (rr & 7)) << 3));
        s16x8 pa1 = *(const s16x8*)(pw + rr * 64 + (((lg + 4) ^ (rr & 7)) << 3));
#pragma unroll
        for (int nd = 0; nd < 4; ++nd) {
            const int d = nd * 16 + l15;
            const u16* vr = Vs + d * 64;
            s16x8 v0 = *(const s16x8*)(vr + ((lg ^ (d & 7)) << 3));
            s16x8 v1 = *(const s16x8*)(vr + (((lg + 4) ^ (d & 7)) << 3));
            o[nd] = MFMA_t(pa1, v1, MFMA_t(pa0, v0, o[nd]));
        }
        __syncthreads();
    }

#pragma unroll
    for (int rg = 0; rg < 4; ++rg) {
        const float inv = 1.f / lsum[rg];
        const int row = qblk * 64 + w * 16 + lg * 4 + rg;
        u16* yp = y + (size_t)(b * TT + row) * 512 + hh * 64;
#pragma unroll
        for (int nd = 0; nd < 4; ++nd) yp[nd * 16 + l15] = f2b(o[nd][rg] * inv);
    }
}

// ---------------------------------------------------------------------------
// V transpose: big[t][1024 + h*64 + d] -> Vt[(bh*64+d)][t]   (bf16)
// ---------------------------------------------------------------------------
__global__ __launch_bounds__(256)
void k_vtrans(const u16* __restrict__ qkv, u16* __restrict__ Vt)
{
    const int g = blockIdx.x * 256 + threadIdx.x;   // 131072 threads
    const int tc = g & 127, d = (g >> 7) & 63, bh = g >> 13;
    const int b = bh >> 3, hh = bh & 7;
    const u16* src = qkv + (size_t)(b * TT + tc * 16) * 1536 + 1024 + hh * 64 + d;
    u16 vals[16];
#pragma unroll
    for (int i = 0; i < 16; ++i) vals[i] = src[(size_t)i * 1536];
    u32 pk[8];
#pragma unroll
    for (int i = 0; i < 8; ++i) pk[i] = (u32)vals[2 * i] | ((u32)vals[2 * i + 1] << 16);
    uint4* dst = (uint4*)(Vt + (size_t)(bh * 64 + d) * 2048 + tc * 16);
    dst[0] = make_uint4(pk[0], pk[1], pk[2], pk[3]);
    dst[1] = make_uint4(pk[4], pk[5], pk[6], pk[7]);
}

// ---------------------------------------------------------------------------
// Weight fp32 [K][N] -> bf16 transposed [N][K]
// ---------------------------------------------------------------------------
__device__ __forceinline__ void wtr(const float* W, u16* Wt, int K, int N, int g)
{
    const int KC = K >> 4;
    const int n = g / KC, kc = g - n * KC;
    const float* src = W + (size_t)(kc * 16) * N + n;
    u32 pk[8];
#pragma unroll
    for (int i = 0; i < 8; ++i) {
        u16 a = f2b(src[(size_t)(2 * i) * N]);
        u16 c = f2b(src[(size_t)(2 * i + 1) * N]);
        pk[i] = (u32)a | ((u32)c << 16);
    }
    uint4* dst = (uint4*)(Wt + (size_t)n * K + kc * 16);
    dst[0] = make_uint4(pk[0], pk[1], pk[2], pk[3]);
    dst[1] = make_uint4(pk[4], pk[5], pk[6], pk[7]);
}

__global__ __launch_bounds__(256)
void k_wtrans(const float* __restrict__ W, u16* __restrict__ Wt, int K, int N)
{
    wtr(W, Wt, K, N, blockIdx.x * 256 + threadIdx.x);
}

__global__ __launch_bounds__(256)
void k_wtrans_layer(const float* __restrict__ Wqkv, const float* __restrict__ Wo,
                    const float* __restrict__ Wf1, const float* __restrict__ Wf2,
                    u16* __restrict__ WqkvT, u16* __restrict__ WoT,
                    u16* __restrict__ Wf1T, u16* __restrict__ Wf2T)
{
    const int blk = blockIdx.x, t = threadIdx.x;
    if (blk < 192)       wtr(Wqkv, WqkvT, 512, 1536, blk * 256 + t);
    else if (blk < 256)  wtr(Wo,   WoT,   512, 512,  (blk - 192) * 256 + t);
    else if (blk < 512)  wtr(Wf1,  Wf1T,  512, 2048, (blk - 256) * 256 + t);
    else                 wtr(Wf2,  Wf2T,  2048, 512, (blk - 512) * 256 + t);
}

// x fp32 -> bf16 (8 elems/thread)
__global__ __launch_bounds__(256)
void k_f2b(const float* __restrict__ x, u16* __restrict__ xb)
{
    const int g = blockIdx.x * 256 + threadIdx.x;
    const float4* s = (const float4*)(x + (size_t)g * 8);
    float4 a = s[0], c = s[1];
    u32 pk[4] = {
        (u32)f2b(a.x) | ((u32)f2b(a.y) << 16), (u32)f2b(a.z) | ((u32)f2b(a.w) << 16),
        (u32)f2b(c.x) | ((u32)f2b(c.y) << 16), (u32)f2b(c.z) | ((u32)f2b(c.w) << 16)};
    *(uint4*)(xb + (size_t)g * 8) = make_uint4(pk[0], pk[1], pk[2], pk[3]);
}

// ---------------------------------------------------------------------------
extern "C" void kernel_launch(void* const* d_in, const int* in_sizes, int n_in,
                              void* d_out, int out_size, void* d_ws, size_t ws_size,
                              hipStream_t stream)
{
    const float* x    = (const float*)d_in[0];
    const float* Win  = (const float*)d_in[1];
    const float* bin_ = (const float*)d_in[2];
    const float* Wqkv = (const float*)d_in[3];
    const float* bqkv = (const float*)d_in[4];
    const float* Wo   = (const float*)d_in[5];
    const float* bo   = (const float*)d_in[6];
    const float* ln1g = (const float*)d_in[7];
    const float* ln1b = (const float*)d_in[8];
    const float* Wf1  = (const float*)d_in[9];
    const float* bf1  = (const float*)d_in[10];
    const float* Wf2  = (const float*)d_in[11];
    const float* bf2  = (const float*)d_in[12];
    const float* ln2g = (const float*)d_in[13];
    const float* ln2b = (const float*)d_in[14];
    const float* lnfg = (const float*)d_in[15];
    const float* lnfb = (const float*)d_in[16];
    const float* Wout = (const float*)d_in[17];
    const float* bout = (const float*)d_in[18];
    float* out = (float*)d_out;

    const int M = 4096;
    char* ws = (char*)d_ws;
    float* h    = (float*)(ws + 0);                 //  8,388,608  fp32 residual
    u16*   y    = (u16*)(ws + 8388608);             //  4,194,304  bf16 LN/attn out
    u16*   big  = (u16*)(ws + 12582912);            // 16,777,216  bf16 qkv/ff1
    u16*   Vt   = big + (size_t)4096 * 1536;        //  tail of big (4 MB)
    u16*   xb   = big;                              //  aliased: only used pre-layer0
    u16*   WinT  = (u16*)(ws + 29360128);
    u16*   WoutT = (u16*)(ws + 29491200);
    u16*   WqkvT = (u16*)(ws + 29622272);
    u16*   WoT   = (u16*)(ws + 31195136);
    u16*   Wf1T  = (u16*)(ws + 31719424);
    u16*   Wf2T  = (u16*)(ws + 33816576);

    dim3 blk(256);

    k_f2b<<<256, blk, 0, stream>>>(x, xb);
    k_wtrans<<<16, blk, 0, stream>>>(Win, WinT, 128, 512);
    k_wtrans<<<16, blk, 0, stream>>>(Wout, WoutT, 512, 128);

    // input projection + sinusoidal PE  -> h (fp32)
    k_gemm_mfma<EPI_PE><<<dim3(4, 32), blk, 0, stream>>>(xb, WinT, bin_, nullptr, h, M, 512, 128);

    for (int lyr = 0; lyr < 4; ++lyr) {
        k_wtrans_layer<<<768, blk, 0, stream>>>(
            Wqkv + (size_t)lyr * 512 * 1536, Wo + (size_t)lyr * 512 * 512,
            Wf1 + (size_t)lyr * 512 * 2048, Wf2 + (size_t)lyr * 2048 * 512,
            WqkvT, WoT, Wf1T, Wf2T);
        k_ln<<<1024, blk, 0, stream>>>(h, ln1g + lyr * 512, ln1b + lyr * 512, y);
        k_gemm_mfma<EPI_QKV><<<dim3(12, 32), blk, 0, stream>>>(
            y, WqkvT, bqkv + lyr * 1536, nullptr, big, M, 1536, 512);
        k_vtrans<<<512, blk, 0, stream>>>(big, Vt);
        k_attn<<<dim3(32, 16), blk, 0, stream>>>(big, Vt, y);
        k_gemm_mfma<EPI_RES><<<dim3(4, 32), blk, 0, stream>>>(
            y, WoT, bo + lyr * 512, h, h, M, 512, 512);
        k_ln<<<1024, blk, 0, stream>>>(h, ln2g + lyr * 512, ln2b + lyr * 512, y);
        k_gemm_mfma<EPI_GELU><<<dim3(16, 32), blk, 0, stream>>>(
            y, Wf1T, bf1 + lyr * 2048, nullptr, big, M, 2048, 512);
        k_gemm_mfma<EPI_RES><<<dim3(4, 32), blk, 0, stream>>>(
            big, Wf2T, bf2 + lyr * 512, h, h, M, 512, 2048);
    }

    k_ln<<<1024, blk, 0, stream>>>(h, lnfg, lnfb, y);
    k_gemm_mfma<EPI_OUTF><<<dim3(1, 32), blk, 0, stream>>>(y, WoutT, bout, nullptr, out, M, 128, 512);
}

// Round 3
// 812.642 us; speedup vs baseline: 5.0673x; 1.0867x over previous
//
#include <hip/hip_runtime.h>
#include <math.h>
#include <type_traits>
#include <utility>

#define TT 2048
typedef unsigned short u16;
typedef unsigned int u32;
typedef float f32x4 __attribute__((ext_vector_type(4)));
typedef float f32x16 __attribute__((ext_vector_type(16)));
typedef short s16x8 __attribute__((ext_vector_type(8)));
typedef __bf16 bf16x8 __attribute__((ext_vector_type(8)));
typedef __bf16 bf16x2 __attribute__((ext_vector_type(2)));
typedef u32 u32x4 __attribute__((ext_vector_type(4)));

enum { EPI_PE = 0, EPI_QKV = 1, EPI_RES = 2, EPI_GELU = 3, EPI_OUTF = 4 };

// ---- MFMA wrappers: handle either builtin signature (v8i16 or v8bf16) ----
template<typename V, typename = void> struct mfma_takes : std::false_type {};
template<typename V> struct mfma_takes<V, std::void_t<decltype(
    __builtin_amdgcn_mfma_f32_16x16x32_bf16(std::declval<V>(), std::declval<V>(),
                                            std::declval<f32x4>(), 0, 0, 0))>>
    : std::true_type {};

template<typename VA>
__device__ __forceinline__ f32x4 MFMA_t(VA a, VA b, f32x4 c) {
    if constexpr (mfma_takes<VA>::value) {
        return __builtin_amdgcn_mfma_f32_16x16x32_bf16(a, b, c, 0, 0, 0);
    } else {
        return __builtin_amdgcn_mfma_f32_16x16x32_bf16(
            __builtin_bit_cast(bf16x8, a), __builtin_bit_cast(bf16x8, b), c, 0, 0, 0);
    }
}

template<typename V, typename = void> struct mfma32_takes : std::false_type {};
template<typename V> struct mfma32_takes<V, std::void_t<decltype(
    __builtin_amdgcn_mfma_f32_32x32x16_bf16(std::declval<V>(), std::declval<V>(),
                                            std::declval<f32x16>(), 0, 0, 0))>>
    : std::true_type {};

template<typename VA>
__device__ __forceinline__ f32x16 MFMA32(VA a, VA b, f32x16 c) {
    if constexpr (mfma32_takes<VA>::value) {
        return __builtin_amdgcn_mfma_f32_32x32x16_bf16(a, b, c, 0, 0, 0);
    } else {
        return __builtin_amdgcn_mfma_f32_32x32x16_bf16(
            __builtin_bit_cast(bf16x8, a), __builtin_bit_cast(bf16x8, b), c, 0, 0, 0);
    }
}

// fp32 -> bf16 RNE
__device__ __forceinline__ u16 f2b(float f) {
    u32 u = __float_as_uint(f);
    return (u16)((u + 0x7FFFu + ((u >> 16) & 1u)) >> 16);
}

// pack two fp32 -> u32 of 2 bf16 (RNE via compiler, may fuse to v_cvt_pk_bf16_f32)
__device__ __forceinline__ u32 pkbf(float a, float b) {
    bf16x2 t; t[0] = (__bf16)a; t[1] = (__bf16)b;
    return __builtin_bit_cast(u32, t);
}

// async global->LDS, 16B per lane; LDS dest = uniform base + lane*16
__device__ __forceinline__ void gload16(const void* g, void* lds_base, int lds_byte_off) {
    __builtin_amdgcn_global_load_lds(
        (const __attribute__((address_space(1))) void*)g,
        (__attribute__((address_space(3))) void*)((char*)lds_base + lds_byte_off),
        16, 0, 0);
}

// ---------------------------------------------------------------------------
// bf16 MFMA GEMM: C[M,N] = A[M,K](bf16 row-major) @ Bt[N,K]^T (bf16) + bias
// 128x128 tile, BK=32, 4 waves (2x2), each wave 64x64 = 4x4 frags of 16x16.
// EPI_QKV: cols<1024 -> bf16 Cout; cols>=1024 (V part) -> transposed Vt.
// ---------------------------------------------------------------------------
template<int EPI>
__global__ __launch_bounds__(256)
void k_gemm_mfma(const u16* __restrict__ A, const u16* __restrict__ Bt,
                 const float* __restrict__ bias, const float* __restrict__ Rf,
                 void* __restrict__ Cout, u16* __restrict__ Vtp, int M, int N, int K)
{
    __shared__ __attribute__((aligned(16))) u16 As[128 * 32];
    __shared__ __attribute__((aligned(16))) u16 Bs[128 * 32];
    const int tid = threadIdx.x;
    const int l = tid & 63, wv = tid >> 6;
    const int l15 = l & 15, lg = l >> 4;
    const int wr = wv >> 1, wc = wv & 1;
    const int row0 = blockIdx.y * 128, col0 = blockIdx.x * 128;

    f32x4 acc[4][4];
#pragma unroll
    for (int m = 0; m < 4; ++m)
#pragma unroll
        for (int n = 0; n < 4; ++n) acc[m][n] = (f32x4){0.f, 0.f, 0.f, 0.f};

    for (int kt = 0; kt < K; kt += 32) {
#pragma unroll
        for (int i = 0; i < 2; ++i) {
            const int u = i * 256 + wv * 64 + l;     // 16B-chunk index, 512 total
            const int ar = u >> 2, ac = u & 3;       // row, stored-chunk
            const int sc = (ac ^ ((ar >> 1) & 3)) << 3;  // source logical chunk *8 elems
            const int off = __builtin_amdgcn_readfirstlane((i * 256 + wv * 64) * 16);
            gload16(A  + (size_t)(row0 + ar) * K + kt + sc, As, off);
            gload16(Bt + (size_t)(col0 + ar) * K + kt + sc, Bs, off);
        }
        __syncthreads();
        s16x8 af[4], bf[4];
#pragma unroll
        for (int m = 0; m < 4; ++m) {
            const int r = wr * 64 + m * 16 + l15;
            af[m] = *(const s16x8*)(As + r * 32 + ((lg ^ ((r >> 1) & 3)) << 3));
        }
#pragma unroll
        for (int n = 0; n < 4; ++n) {
            const int r = wc * 64 + n * 16 + l15;
            bf[n] = *(const s16x8*)(Bs + r * 32 + ((lg ^ ((r >> 1) & 3)) << 3));
        }
#pragma unroll
        for (int m = 0; m < 4; ++m)
#pragma unroll
            for (int n = 0; n < 4; ++n) acc[m][n] = MFMA_t(af[m], bf[n], acc[m][n]);
        __syncthreads();
    }

#pragma unroll
    for (int m = 0; m < 4; ++m)
#pragma unroll
        for (int rg = 0; rg < 4; ++rg) {
            const int row = row0 + wr * 64 + m * 16 + lg * 4 + rg;
#pragma unroll
            for (int n = 0; n < 4; ++n) {
                const int col = col0 + wc * 64 + n * 16 + l15;
                float v = acc[m][n][rg] + bias[col];
                const size_t idx = (size_t)row * N + col;
                if constexpr (EPI == EPI_PE) {
                    const int t = row & (TT - 1);
                    const float freq = __expf(-(float)(col & ~1) * 0.017988946039015984f);
                    const float ang = (float)t * freq;
                    v += (col & 1) ? cosf(ang) : sinf(ang);
                    ((float*)Cout)[idx] = v;
                } else if constexpr (EPI == EPI_QKV) {
                    if (col < 1024) {
                        ((u16*)Cout)[idx] = f2b(v);
                    } else {
                        const int cv = col - 1024, hh2 = cv >> 6, dd = cv & 63;
                        const int bb2 = row >> 11, t2 = row & (TT - 1);
                        Vtp[((size_t)(bb2 * 8 + hh2) * 64 + dd) * TT + t2] = f2b(v);
                    }
                } else if constexpr (EPI == EPI_GELU) {
                    v = 0.5f * v * (1.f + erff(v * 0.7071067811865475f));
                    ((u16*)Cout)[idx] = f2b(v);
                } else if constexpr (EPI == EPI_RES) {
                    ((float*)Cout)[idx] = Rf[idx] + v;
                } else {
                    ((float*)Cout)[idx] = v;
                }
            }
        }
}

// ---------------------------------------------------------------------------
// LayerNorm D=512: h(fp32) -> y(bf16). One wave per row.
// ---------------------------------------------------------------------------
__global__ __launch_bounds__(256)
void k_ln(const float* __restrict__ X, const float* __restrict__ g,
          const float* __restrict__ b, u16* __restrict__ Y)
{
    const int lane = threadIdx.x & 63;
    const int row = blockIdx.x * 4 + (threadIdx.x >> 6);
    const float* x = X + (size_t)row * 512 + lane * 8;

    float4 v0 = *(const float4*)x;
    float4 v1 = *(const float4*)(x + 4);
    float vals[8] = {v0.x, v0.y, v0.z, v0.w, v1.x, v1.y, v1.z, v1.w};

    float s = 0.f;
#pragma unroll
    for (int i = 0; i < 8; ++i) s += vals[i];
#pragma unroll
    for (int off = 32; off >= 1; off >>= 1) s += __shfl_xor(s, off);
    const float mu = s * (1.f / 512.f);

    float sq = 0.f;
#pragma unroll
    for (int i = 0; i < 8; ++i) { float d = vals[i] - mu; sq += d * d; }
#pragma unroll
    for (int off = 32; off >= 1; off >>= 1) sq += __shfl_xor(sq, off);
    const float rs = rsqrtf(sq * (1.f / 512.f) + 1e-5f);

    const float* gp = g + lane * 8;
    const float* bp = b + lane * 8;
    float4 g0 = *(const float4*)gp, g1 = *(const float4*)(gp + 4);
    float4 b0 = *(const float4*)bp, b1 = *(const float4*)(bp + 4);
    float ga[8] = {g0.x, g0.y, g0.z, g0.w, g1.x, g1.y, g1.z, g1.w};
    float bb[8] = {b0.x, b0.y, b0.z, b0.w, b1.x, b1.y, b1.z, b1.w};

    u32 pk[4];
#pragma unroll
    for (int i = 0; i < 4; ++i) {
        float a0 = (vals[2 * i]     - mu) * rs * ga[2 * i]     + bb[2 * i];
        float a1 = (vals[2 * i + 1] - mu) * rs * ga[2 * i + 1] + bb[2 * i + 1];
        pk[i] = (u32)f2b(a0) | ((u32)f2b(a1) << 16);
    }
    *(uint4*)(Y + (size_t)row * 512 + lane * 8) = make_uint4(pk[0], pk[1], pk[2], pk[3]);
}

// ---------------------------------------------------------------------------
// Causal flash attention, swapped-operand 32x32x16 MFMA.
// Grid (16 pairs, 16 bh), 256 threads = 4 waves.
// Block (a,bh): waves 0,1 -> q-tile a (rows a*64 + w*32), waves 2,3 -> q-tile
// 31-a. Shared kv loop kb=0..31-a, K/V staged once for both tiles, double-
// buffered via global_load_lds + counted vmcnt + raw s_barrier (no drain).
// S^T = mfma32(K,Q): lane holds ONE q (col=l&31), 32 kv (rows). Softmax:
// in-lane tree + one shfl_xor(32). P->A-frag: 16 packs + shfl_xor(32)
// exchange (in-register, no LDS). O^T = mfma32(Vt,P): per-lane q rescale.
// ---------------------------------------------------------------------------
__global__ __launch_bounds__(256)
void k_attn(const u16* __restrict__ qkv, const u16* __restrict__ Vt, u16* __restrict__ y)
{
    __shared__ __attribute__((aligned(16))) u16 KsA[2 * 64 * 64];
    __shared__ __attribute__((aligned(16))) u16 VsA[2 * 64 * 64];
    const int tid = threadIdx.x;
    const int l = tid & 63, w = tid >> 6;
    const int l31 = l & 31, hi = l >> 5;
    const int a = blockIdx.x, bh = blockIdx.y;
    const int b = bh >> 3, hh = bh & 7;
    const int bT = b * TT, hh64 = hh * 64;

    const int qb = (w < 2) ? a : (31 - a);       // q-tile (64-row units)
    const int q0 = qb * 64 + (w & 1) * 32;       // wave's q base (32 rows)
    const int qg = q0 + l31;                     // this lane's q row
    const int kbmax = 31 - a;

    // ---- staging helper: K tile [64 kv][64 d], Vt tile [64 d][64 kv], swizzled
    auto STAGE = [&](int kb, int buf) {
#pragma unroll
        for (int i = 0; i < 2; ++i) {
            const int u = i * 256 + tid;
            const int r = u >> 3, c = u & 7;
            const int sc = (c ^ (r & 7)) << 3;
            const int off = __builtin_amdgcn_readfirstlane(
                (i * 256 + w * 64) * 16 + buf * 8192);
            gload16(qkv + (size_t)(bT + kb * 64 + r) * 1536 + 512 + hh64 + sc, KsA, off);
            gload16(Vt + (size_t)(bh * 64 + r) * TT + kb * 64 + sc, VsA, off);
        }
    };

    STAGE(0, 0);

    // Q B-frags: lane holds q-row qg, d-chunk dk*16 + hi*8
    s16x8 qf[4];
    {
        const u16* qsrc = qkv + (size_t)(bT + qg) * 1536 + hh64 + hi * 8;
#pragma unroll
        for (int dk = 0; dk < 4; ++dk) qf[dk] = *(const s16x8*)(qsrc + dk * 16);
    }

    f32x16 o[2] = {};
    float m = -1e30f, lsum = 0.f;

    asm volatile("s_waitcnt vmcnt(0)" ::: "memory");
    __builtin_amdgcn_s_barrier();

    for (int kb = 0; kb <= kbmax; ++kb) {
        const int cur = kb & 1;
        if (kb < kbmax) {
            STAGE(kb + 1, cur ^ 1);
            asm volatile("s_waitcnt vmcnt(4)" ::: "memory");
        } else {
            asm volatile("s_waitcnt vmcnt(0)" ::: "memory");
        }
        __builtin_amdgcn_s_barrier();
        __builtin_amdgcn_sched_barrier(0);

        if (kb <= qb) {                       // wave-uniform: this q-tile active
            const u16* kbase = KsA + cur * 4096;
            const u16* vbase = VsA + cur * 4096;

            // S^T = K Q^T over d=64 (4 chained mfma per 32-kv subtile)
            f32x16 sA[2];
#pragma unroll
            for (int nb = 0; nb < 2; ++nb) {
                const int krow = nb * 32 + l31;
                const u16* kr = kbase + krow * 64;
                f32x16 acc = {};
#pragma unroll
                for (int dk = 0; dk < 4; ++dk) {
                    s16x8 kf = *(const s16x8*)(kr + (((dk * 2 + hi) ^ (krow & 7)) << 3));
                    acc = MFMA32(kf, qf[dk], acc);
                }
                sA[nb] = acc;
            }

            // causal mask on diagonal supertile
            if (kb == qb) {
                const int kvb = kb * 64, hi4 = hi * 4;
#pragma unroll
                for (int nb = 0; nb < 2; ++nb)
#pragma unroll
                    for (int r = 0; r < 16; ++r) {
                        const int kv = kvb + nb * 32 + (r & 3) + 8 * (r >> 2) + hi4;
                        sA[nb][r] = (kv > qg) ? -1e30f : sA[nb][r];
                    }
            }

            // online softmax (scale 1/8 folded into exp)
            float tmp[16];
#pragma unroll
            for (int r = 0; r < 16; ++r) tmp[r] = fmaxf(sA[0][r], sA[1][r]);
#pragma unroll
            for (int st = 8; st >= 1; st >>= 1)
#pragma unroll
                for (int r = 0; r < 8; ++r)
                    if (r < st) tmp[r] = fmaxf(tmp[r], tmp[r + st]);
            float mt = fmaxf(tmp[0], __shfl_xor(tmp[0], 32));
            const float mn = fmaxf(m, mt);
            const float alpha = __expf((m - mn) * 0.125f);
            m = mn;
            const float mc = -mn * 0.125f;

            float p[2][16];
            float sum[16];
#pragma unroll
            for (int r = 0; r < 16; ++r) {
                p[0][r] = __expf(fmaf(sA[0][r], 0.125f, mc));
                p[1][r] = __expf(fmaf(sA[1][r], 0.125f, mc));
                sum[r] = p[0][r] + p[1][r];
            }
#pragma unroll
            for (int st = 8; st >= 1; st >>= 1)
#pragma unroll
                for (int r = 0; r < 8; ++r)
                    if (r < st) sum[r] += sum[r + st];
            float psum = sum[0] + __shfl_xor(sum[0], 32);
            lsum = lsum * alpha + psum;
#pragma unroll
            for (int dt = 0; dt < 2; ++dt)
#pragma unroll
                for (int r = 0; r < 16; ++r) o[dt][r] *= alpha;

            // P (f32, D-layout) -> bf16 A-frags via lane<->lane+32 exchange
            u32 pk2[2][8], sw2[2][8];
#pragma unroll
            for (int nb = 0; nb < 2; ++nb)
#pragma unroll
                for (int i = 0; i < 8; ++i) {
                    pk2[nb][i] = pkbf(p[nb][2 * i], p[nb][2 * i + 1]);
                    sw2[nb][i] = __shfl_xor(pk2[nb][i], 32);
                }
            s16x8 pa[4];
#pragma unroll
            for (int nb = 0; nb < 2; ++nb)
#pragma unroll
                for (int k16 = 0; k16 < 2; ++k16) {
                    const int i0 = k16 * 4;
                    u32 w0 = hi ? sw2[nb][i0 + 2] : pk2[nb][i0 + 0];
                    u32 w1 = hi ? sw2[nb][i0 + 3] : pk2[nb][i0 + 1];
                    u32 w2 = hi ? pk2[nb][i0 + 2] : sw2[nb][i0 + 0];
                    u32 w3 = hi ? pk2[nb][i0 + 3] : sw2[nb][i0 + 1];
                    u32x4 t4 = {w0, w1, w2, w3};
                    pa[nb * 2 + k16] = __builtin_bit_cast(s16x8, t4);
                }

            // O^T += V^T P^T  (A = Vt rows d, B = P rows q)
#pragma unroll
            for (int dt = 0; dt < 2; ++dt) {
                const int vrow = dt * 32 + l31;
                const u16* vr = vbase + vrow * 64;
                f32x16 acc = o[dt];
#pragma unroll
                for (int ks = 0; ks < 4; ++ks) {
                    s16x8 vf = *(const s16x8*)(vr + (((ks * 2 + hi) ^ (vrow & 7)) << 3));
                    acc = MFMA32(vf, pa[ks], acc);
                }
                o[dt] = acc;
            }
        }

        __builtin_amdgcn_sched_barrier(0);
        asm volatile("" ::: "memory");
        __builtin_amdgcn_s_barrier();
    }

    // write O^T: lane q = qg, d = dt*32 + (reg&3)+8*(reg>>2)+4*hi
    const float inv = 1.f / lsum;
    u16* yrow = y + (size_t)(bT + qg) * 512 + hh64;
#pragma unroll
    for (int dt = 0; dt < 2; ++dt)
#pragma unroll
        for (int i = 0; i < 8; ++i) {
            const int d = dt * 32 + ((2 * i) & 3) + 8 * (i >> 1) + 4 * hi;
            *(u32*)(yrow + d) = pkbf(o[dt][2 * i] * inv, o[dt][2 * i + 1] * inv);
        }
}

// ---------------------------------------------------------------------------
// Weight fp32 [K][N] -> bf16 transposed [N][K]
// ---------------------------------------------------------------------------
__device__ __forceinline__ void wtr(const float* W, u16* Wt, int K, int N, int g)
{
    const int KC = K >> 4;
    const int n = g / KC, kc = g - n * KC;
    const float* src = W + (size_t)(kc * 16) * N + n;
    u32 pk[8];
#pragma unroll
    for (int i = 0; i < 8; ++i) {
        u16 a = f2b(src[(size_t)(2 * i) * N]);
        u16 c = f2b(src[(size_t)(2 * i + 1) * N]);
        pk[i] = (u32)a | ((u32)c << 16);
    }
    uint4* dst = (uint4*)(Wt + (size_t)n * K + kc * 16);
    dst[0] = make_uint4(pk[0], pk[1], pk[2], pk[3]);
    dst[1] = make_uint4(pk[4], pk[5], pk[6], pk[7]);
}

__global__ __launch_bounds__(256)
void k_wtrans(const float* __restrict__ W, u16* __restrict__ Wt, int K, int N)
{
    wtr(W, Wt, K, N, blockIdx.x * 256 + threadIdx.x);
}

__global__ __launch_bounds__(256)
void k_wtrans_layer(const float* __restrict__ Wqkv, const float* __restrict__ Wo,
                    const float* __restrict__ Wf1, const float* __restrict__ Wf2,
                    u16* __restrict__ WqkvT, u16* __restrict__ WoT,
                    u16* __restrict__ Wf1T, u16* __restrict__ Wf2T)
{
    const int blk = blockIdx.x, t = threadIdx.x;
    if (blk < 192)       wtr(Wqkv, WqkvT, 512, 1536, blk * 256 + t);
    else if (blk < 256)  wtr(Wo,   WoT,   512, 512,  (blk - 192) * 256 + t);
    else if (blk < 512)  wtr(Wf1,  Wf1T,  512, 2048, (blk - 256) * 256 + t);
    else                 wtr(Wf2,  Wf2T,  2048, 512, (blk - 512) * 256 + t);
}

// x fp32 -> bf16 (8 elems/thread)
__global__ __launch_bounds__(256)
void k_f2b(const float* __restrict__ x, u16* __restrict__ xb)
{
    const int g = blockIdx.x * 256 + threadIdx.x;
    const float4* s = (const float4*)(x + (size_t)g * 8);
    float4 a = s[0], c = s[1];
    u32 pk[4] = {
        (u32)f2b(a.x) | ((u32)f2b(a.y) << 16), (u32)f2b(a.z) | ((u32)f2b(a.w) << 16),
        (u32)f2b(c.x) | ((u32)f2b(c.y) << 16), (u32)f2b(c.z) | ((u32)f2b(c.w) << 16)};
    *(uint4*)(xb + (size_t)g * 8) = make_uint4(pk[0], pk[1], pk[2], pk[3]);
}

// ---------------------------------------------------------------------------
extern "C" void kernel_launch(void* const* d_in, const int* in_sizes, int n_in,
                              void* d_out, int out_size, void* d_ws, size_t ws_size,
                              hipStream_t stream)
{
    const float* x    = (const float*)d_in[0];
    const float* Win  = (const float*)d_in[1];
    const float* bin_ = (const float*)d_in[2];
    const float* Wqkv = (const float*)d_in[3];
    const float* bqkv = (const float*)d_in[4];
    const float* Wo   = (const float*)d_in[5];
    const float* bo   = (const float*)d_in[6];
    const float* ln1g = (const float*)d_in[7];
    const float* ln1b = (const float*)d_in[8];
    const float* Wf1  = (const float*)d_in[9];
    const float* bf1  = (const float*)d_in[10];
    const float* Wf2  = (const float*)d_in[11];
    const float* bf2  = (const float*)d_in[12];
    const float* ln2g = (const float*)d_in[13];
    const float* ln2b = (const float*)d_in[14];
    const float* lnfg = (const float*)d_in[15];
    const float* lnfb = (const float*)d_in[16];
    const float* Wout = (const float*)d_in[17];
    const float* bout = (const float*)d_in[18];
    float* out = (float*)d_out;

    const int M = 4096;
    char* ws = (char*)d_ws;
    float* h    = (float*)(ws + 0);                 //  8,388,608  fp32 residual
    u16*   y    = (u16*)(ws + 8388608);             //  4,194,304  bf16 LN/attn out
    u16*   big  = (u16*)(ws + 12582912);            // 16,777,216  bf16 qkv/ff1
    u16*   Vt   = big + (size_t)4096 * 1536;        //  tail of big (4 MB)
    u16*   xb   = big;                              //  aliased: only used pre-layer0
    u16*   WinT  = (u16*)(ws + 29360128);
    u16*   WoutT = (u16*)(ws + 29491200);
    u16*   WqkvT = (u16*)(ws + 29622272);
    u16*   WoT   = (u16*)(ws + 31195136);
    u16*   Wf1T  = (u16*)(ws + 31719424);
    u16*   Wf2T  = (u16*)(ws + 33816576);

    dim3 blk(256);

    k_f2b<<<256, blk, 0, stream>>>(x, xb);
    k_wtrans<<<16, blk, 0, stream>>>(Win, WinT, 128, 512);
    k_wtrans<<<16, blk, 0, stream>>>(Wout, WoutT, 512, 128);

    // input projection + sinusoidal PE  -> h (fp32)
    k_gemm_mfma<EPI_PE><<<dim3(4, 32), blk, 0, stream>>>(
        xb, WinT, bin_, nullptr, h, nullptr, M, 512, 128);

    for (int lyr = 0; lyr < 4; ++lyr) {
        k_wtrans_layer<<<768, blk, 0, stream>>>(
            Wqkv + (size_t)lyr * 512 * 1536, Wo + (size_t)lyr * 512 * 512,
            Wf1 + (size_t)lyr * 512 * 2048, Wf2 + (size_t)lyr * 2048 * 512,
            WqkvT, WoT, Wf1T, Wf2T);
        k_ln<<<1024, blk, 0, stream>>>(h, ln1g + lyr * 512, ln1b + lyr * 512, y);
        k_gemm_mfma<EPI_QKV><<<dim3(12, 32), blk, 0, stream>>>(
            y, WqkvT, bqkv + lyr * 1536, nullptr, big, Vt, M, 1536, 512);
        k_attn<<<dim3(16, 16), blk, 0, stream>>>(big, Vt, y);
        k_gemm_mfma<EPI_RES><<<dim3(4, 32), blk, 0, stream>>>(
            y, WoT, bo + lyr * 512, h, h, nullptr, M, 512, 512);
        k_ln<<<1024, blk, 0, stream>>>(h, ln2g + lyr * 512, ln2b + lyr * 512, y);
        k_gemm_mfma<EPI_GELU><<<dim3(16, 32), blk, 0, stream>>>(
            y, Wf1T, bf1 + lyr * 2048, nullptr, big, nullptr, M, 2048, 512);
        k_gemm_mfma<EPI_RES><<<dim3(4, 32), blk, 0, stream>>>(
            big, Wf2T, bf2 + lyr * 512, h, h, nullptr, M, 512, 2048);
    }

    k_ln<<<1024, blk, 0, stream>>>(h, lnfg, lnfb, y);
    k_gemm_mfma<EPI_OUTF><<<dim3(1, 32), blk, 0, stream>>>(
        y, WoutT, bout, nullptr, out, nullptr, M, 128, 512);
}

// Round 4
// 643.069 us; speedup vs baseline: 6.4035x; 1.2637x over previous
//
#include <hip/hip_runtime.h>
#include <math.h>
#include <type_traits>
#include <utility>

#define TT 2048
typedef unsigned short u16;
typedef unsigned int u32;
typedef float f32x4 __attribute__((ext_vector_type(4)));
typedef float f32x16 __attribute__((ext_vector_type(16)));
typedef short s16x8 __attribute__((ext_vector_type(8)));
typedef __bf16 bf16x8 __attribute__((ext_vector_type(8)));
typedef __bf16 bf16x2 __attribute__((ext_vector_type(2)));
typedef u32 u32x4 __attribute__((ext_vector_type(4)));

enum { EPI_PE = 0, EPI_BF16 = 1, EPI_RES = 2, EPI_GELU = 3, EPI_OUTF = 4 };

// ---- MFMA wrappers: handle either builtin signature (v8i16 or v8bf16) ----
template<typename V, typename = void> struct mfma_takes : std::false_type {};
template<typename V> struct mfma_takes<V, std::void_t<decltype(
    __builtin_amdgcn_mfma_f32_16x16x32_bf16(std::declval<V>(), std::declval<V>(),
                                            std::declval<f32x4>(), 0, 0, 0))>>
    : std::true_type {};

template<typename VA>
__device__ __forceinline__ f32x4 MFMA_t(VA a, VA b, f32x4 c) {
    if constexpr (mfma_takes<VA>::value) {
        return __builtin_amdgcn_mfma_f32_16x16x32_bf16(a, b, c, 0, 0, 0);
    } else {
        return __builtin_amdgcn_mfma_f32_16x16x32_bf16(
            __builtin_bit_cast(bf16x8, a), __builtin_bit_cast(bf16x8, b), c, 0, 0, 0);
    }
}

template<typename V, typename = void> struct mfma32_takes : std::false_type {};
template<typename V> struct mfma32_takes<V, std::void_t<decltype(
    __builtin_amdgcn_mfma_f32_32x32x16_bf16(std::declval<V>(), std::declval<V>(),
                                            std::declval<f32x16>(), 0, 0, 0))>>
    : std::true_type {};

template<typename VA>
__device__ __forceinline__ f32x16 MFMA32(VA a, VA b, f32x16 c) {
    if constexpr (mfma32_takes<VA>::value) {
        return __builtin_amdgcn_mfma_f32_32x32x16_bf16(a, b, c, 0, 0, 0);
    } else {
        return __builtin_amdgcn_mfma_f32_32x32x16_bf16(
            __builtin_bit_cast(bf16x8, a), __builtin_bit_cast(bf16x8, b), c, 0, 0, 0);
    }
}

// fp32 -> bf16 RNE
__device__ __forceinline__ u16 f2b(float f) {
    u32 u = __float_as_uint(f);
    return (u16)((u + 0x7FFFu + ((u >> 16) & 1u)) >> 16);
}

__device__ __forceinline__ u32 pkbf(float a, float b) {
    bf16x2 t; t[0] = (__bf16)a; t[1] = (__bf16)b;
    return __builtin_bit_cast(u32, t);
}

// async global->LDS, 16B per lane; LDS dest = uniform base + lane*16
__device__ __forceinline__ void gload16(const void* g, void* lds_base, int lds_byte_off) {
    __builtin_amdgcn_global_load_lds(
        (const __attribute__((address_space(1))) void*)g,
        (__attribute__((address_space(3))) void*)((char*)lds_base + lds_byte_off),
        16, 0, 0);
}

// ---------------------------------------------------------------------------
// bf16 MFMA GEMM: C[M,N] = A[M,K](bf16 rm) @ Bt[N,K]^T (bf16) + bias
// Tile TM x 128, BK=32, 4 waves (2x2). TM=128: wave 64x64 (4x4 frags);
// TM=64: wave 32x64 (2x4 frags) - for small-N GEMMs (2x the blocks).
// ---------------------------------------------------------------------------
template<int EPI, int TM>
__global__ __launch_bounds__(256)
void k_gemm_mfma(const u16* __restrict__ A, const u16* __restrict__ Bt,
                 const float* __restrict__ bias, const float* __restrict__ Rf,
                 void* __restrict__ Cout, int M, int N, int K)
{
    constexpr int MF = TM / 32;                 // m-frags per wave
    __shared__ __attribute__((aligned(16))) u16 As[TM * 32];
    __shared__ __attribute__((aligned(16))) u16 Bs[128 * 32];
    const int tid = threadIdx.x;
    const int l = tid & 63, wv = tid >> 6;
    const int l15 = l & 15, lg = l >> 4;
    const int wr = wv >> 1, wc = wv & 1;
    const int row0 = blockIdx.y * TM, col0 = blockIdx.x * 128;

    f32x4 acc[MF][4];
#pragma unroll
    for (int m = 0; m < MF; ++m)
#pragma unroll
        for (int n = 0; n < 4; ++n) acc[m][n] = (f32x4){0.f, 0.f, 0.f, 0.f};

    for (int kt = 0; kt < K; kt += 32) {
#pragma unroll
        for (int i = 0; i < TM / 64; ++i) {          // A: TM*4 chunks of 16B
            const int u = i * 256 + wv * 64 + l;
            const int ar = u >> 2, ac = u & 3;
            const int sc = (ac ^ ((ar >> 1) & 3)) << 3;
            const int off = __builtin_amdgcn_readfirstlane((i * 256 + wv * 64) * 16);
            gload16(A + (size_t)(row0 + ar) * K + kt + sc, As, off);
        }
#pragma unroll
        for (int i = 0; i < 2; ++i) {                // B: 512 chunks
            const int u = i * 256 + wv * 64 + l;
            const int ar = u >> 2, ac = u & 3;
            const int sc = (ac ^ ((ar >> 1) & 3)) << 3;
            const int off = __builtin_amdgcn_readfirstlane((i * 256 + wv * 64) * 16);
            gload16(Bt + (size_t)(col0 + ar) * K + kt + sc, Bs, off);
        }
        __syncthreads();
        s16x8 af[MF], bf[4];
#pragma unroll
        for (int m = 0; m < MF; ++m) {
            const int r = wr * (TM / 2) + m * 16 + l15;
            af[m] = *(const s16x8*)(As + r * 32 + ((lg ^ ((r >> 1) & 3)) << 3));
        }
#pragma unroll
        for (int n = 0; n < 4; ++n) {
            const int r = wc * 64 + n * 16 + l15;
            bf[n] = *(const s16x8*)(Bs + r * 32 + ((lg ^ ((r >> 1) & 3)) << 3));
        }
#pragma unroll
        for (int m = 0; m < MF; ++m)
#pragma unroll
            for (int n = 0; n < 4; ++n) acc[m][n] = MFMA_t(af[m], bf[n], acc[m][n]);
        __syncthreads();
    }

#pragma unroll
    for (int m = 0; m < MF; ++m)
#pragma unroll
        for (int rg = 0; rg < 4; ++rg) {
            const int row = row0 + wr * (TM / 2) + m * 16 + lg * 4 + rg;
#pragma unroll
            for (int n = 0; n < 4; ++n) {
                const int col = col0 + wc * 64 + n * 16 + l15;
                float v = acc[m][n][rg] + bias[col];
                const size_t idx = (size_t)row * N + col;
                if constexpr (EPI == EPI_PE) {
                    const int t = row & (TT - 1);
                    const float freq = __expf(-(float)(col & ~1) * 0.017988946039015984f);
                    const float ang = (float)t * freq;
                    v += (col & 1) ? cosf(ang) : sinf(ang);
                    ((float*)Cout)[idx] = v;
                } else if constexpr (EPI == EPI_BF16) {
                    ((u16*)Cout)[idx] = f2b(v);
                } else if constexpr (EPI == EPI_GELU) {
                    v = 0.5f * v * (1.f + erff(v * 0.7071067811865475f));
                    ((u16*)Cout)[idx] = f2b(v);
                } else if constexpr (EPI == EPI_RES) {
                    ((float*)Cout)[idx] = Rf[idx] + v;
                } else {
                    ((float*)Cout)[idx] = v;
                }
            }
        }
}

// ---------------------------------------------------------------------------
// LayerNorm D=512: h(fp32) -> y(bf16). One wave per row.
// ---------------------------------------------------------------------------
__global__ __launch_bounds__(256)
void k_ln(const float* __restrict__ X, const float* __restrict__ g,
          const float* __restrict__ b, u16* __restrict__ Y)
{
    const int lane = threadIdx.x & 63;
    const int row = blockIdx.x * 4 + (threadIdx.x >> 6);
    const float* x = X + (size_t)row * 512 + lane * 8;

    float4 v0 = *(const float4*)x;
    float4 v1 = *(const float4*)(x + 4);
    float vals[8] = {v0.x, v0.y, v0.z, v0.w, v1.x, v1.y, v1.z, v1.w};

    float s = 0.f;
#pragma unroll
    for (int i = 0; i < 8; ++i) s += vals[i];
#pragma unroll
    for (int off = 32; off >= 1; off >>= 1) s += __shfl_xor(s, off);
    const float mu = s * (1.f / 512.f);

    float sq = 0.f;
#pragma unroll
    for (int i = 0; i < 8; ++i) { float d = vals[i] - mu; sq += d * d; }
#pragma unroll
    for (int off = 32; off >= 1; off >>= 1) sq += __shfl_xor(sq, off);
    const float rs = rsqrtf(sq * (1.f / 512.f) + 1e-5f);

    const float* gp = g + lane * 8;
    const float* bp = b + lane * 8;
    float4 g0 = *(const float4*)gp, g1 = *(const float4*)(gp + 4);
    float4 b0 = *(const float4*)bp, b1 = *(const float4*)(bp + 4);
    float ga[8] = {g0.x, g0.y, g0.z, g0.w, g1.x, g1.y, g1.z, g1.w};
    float bb[8] = {b0.x, b0.y, b0.z, b0.w, b1.x, b1.y, b1.z, b1.w};

    u32 pk[4];
#pragma unroll
    for (int i = 0; i < 4; ++i) {
        float a0 = (vals[2 * i]     - mu) * rs * ga[2 * i]     + bb[2 * i];
        float a1 = (vals[2 * i + 1] - mu) * rs * ga[2 * i + 1] + bb[2 * i + 1];
        pk[i] = (u32)f2b(a0) | ((u32)f2b(a1) << 16);
    }
    *(uint4*)(Y + (size_t)row * 512 + lane * 8) = make_uint4(pk[0], pk[1], pk[2], pk[3]);
}

// ---------------------------------------------------------------------------
// Causal flash attention, LDS-free. 1024 blocks x 64 threads (1 wave each).
// Block -> (bh, 32-row q-tile) via XCD swizzle (2 bh per XCD -> K/V L2-hot)
// + LPT order (longest tiles first). K/V frags load 16B straight from L2.
// S^T = mfma32(K,Q), softmax in-register, P repack via shfl_xor(32),
// O^T = mfma32(Vt,P). No barriers, no LDS, no vmcnt games.
// ---------------------------------------------------------------------------
__global__ __launch_bounds__(64)
void k_attn(const u16* __restrict__ qkv, const u16* __restrict__ Vt, u16* __restrict__ y)
{
    const int l = threadIdx.x;
    const int l31 = l & 31, hi = l >> 5;
    // swizzle: xcd = bx&7 gets bh {2*xcd, 2*xcd+1}; t descends (LPT)
    const int bx = blockIdx.x;
    const int xcd = bx & 7, s = bx >> 3;
    const int bh = xcd * 2 + (s & 1);
    const int t_tile = 63 - (s >> 1);
    const int b = bh >> 3, hh = bh & 7;
    const int bT = b * TT, hh64 = hh * 64;

    const int qg = t_tile * 32 + l31;
    const int myKb = (t_tile * 32 + 31) >> 6;    // last 64-wide kv tile needed

    // Q B-frags
    s16x8 qf[4];
    {
        const u16* qsrc = qkv + (size_t)(bT + qg) * 1536 + hh64 + hi * 8;
#pragma unroll
        for (int dk = 0; dk < 4; ++dk) qf[dk] = *(const s16x8*)(qsrc + dk * 16);
    }

    s16x8 kf[8];
    auto LOADK = [&](int kb) {
#pragma unroll
        for (int nb = 0; nb < 2; ++nb) {
            const u16* kr = qkv + (size_t)(bT + kb * 64 + nb * 32 + l31) * 1536
                            + 512 + hh64 + hi * 8;
#pragma unroll
            for (int dk = 0; dk < 4; ++dk)
                kf[nb * 4 + dk] = *(const s16x8*)(kr + dk * 16);
        }
    };
    LOADK(0);

    f32x16 o[2] = {};
    float m = -1e30f, lsum = 0.f;

    for (int kb = 0; kb <= myKb; ++kb) {
        // S^T = K Q^T over d=64
        f32x16 sA[2];
#pragma unroll
        for (int nb = 0; nb < 2; ++nb) {
            f32x16 acc = {};
#pragma unroll
            for (int dk = 0; dk < 4; ++dk) acc = MFMA32(kf[nb * 4 + dk], qf[dk], acc);
            sA[nb] = acc;
        }
        if (kb < myKb) LOADK(kb + 1);   // prefetch next K under softmax/PV

        // causal mask on the diagonal supertile
        if (kb == myKb) {
            const int kvb = kb * 64, hi4 = hi * 4;
#pragma unroll
            for (int nb = 0; nb < 2; ++nb)
#pragma unroll
                for (int r = 0; r < 16; ++r) {
                    const int kv = kvb + nb * 32 + (r & 3) + 8 * (r >> 2) + hi4;
                    sA[nb][r] = (kv > qg) ? -1e30f : sA[nb][r];
                }
        }

        // online softmax (scale 1/8 folded into exp)
        float tmp[16];
#pragma unroll
        for (int r = 0; r < 16; ++r) tmp[r] = fmaxf(sA[0][r], sA[1][r]);
#pragma unroll
        for (int st = 8; st >= 1; st >>= 1)
#pragma unroll
            for (int r = 0; r < 8; ++r)
                if (r < st) tmp[r] = fmaxf(tmp[r], tmp[r + st]);
        float mt = fmaxf(tmp[0], __shfl_xor(tmp[0], 32));
        const float mn = fmaxf(m, mt);
        const float alpha = __expf((m - mn) * 0.125f);
        m = mn;
        const float mc = -mn * 0.125f;

        float p[2][16];
        float sum[16];
#pragma unroll
        for (int r = 0; r < 16; ++r) {
            p[0][r] = __expf(fmaf(sA[0][r], 0.125f, mc));
            p[1][r] = __expf(fmaf(sA[1][r], 0.125f, mc));
            sum[r] = p[0][r] + p[1][r];
        }
#pragma unroll
        for (int st = 8; st >= 1; st >>= 1)
#pragma unroll
            for (int r = 0; r < 8; ++r)
                if (r < st) sum[r] += sum[r + st];
        float psum = sum[0] + __shfl_xor(sum[0], 32);
        lsum = lsum * alpha + psum;
#pragma unroll
        for (int dt = 0; dt < 2; ++dt)
#pragma unroll
            for (int r = 0; r < 16; ++r) o[dt][r] *= alpha;

        // P (f32, D-layout) -> bf16 A-frags via lane<->lane+32 exchange
        u32 pk2[2][8], sw2[2][8];
#pragma unroll
        for (int nb = 0; nb < 2; ++nb)
#pragma unroll
            for (int i = 0; i < 8; ++i) {
                pk2[nb][i] = pkbf(p[nb][2 * i], p[nb][2 * i + 1]);
                sw2[nb][i] = __shfl_xor(pk2[nb][i], 32);
            }
        s16x8 pa[4];
#pragma unroll
        for (int nb = 0; nb < 2; ++nb)
#pragma unroll
            for (int k16 = 0; k16 < 2; ++k16) {
                const int i0 = k16 * 4;
                u32 w0 = hi ? sw2[nb][i0 + 2] : pk2[nb][i0 + 0];
                u32 w1 = hi ? sw2[nb][i0 + 3] : pk2[nb][i0 + 1];
                u32 w2 = hi ? pk2[nb][i0 + 2] : sw2[nb][i0 + 0];
                u32 w3 = hi ? pk2[nb][i0 + 3] : sw2[nb][i0 + 1];
                u32x4 t4 = {w0, w1, w2, w3};
                pa[nb * 2 + k16] = __builtin_bit_cast(s16x8, t4);
            }

        // O^T += V^T P^T, V frags straight from L2
#pragma unroll
        for (int dt = 0; dt < 2; ++dt) {
            const u16* vr = Vt + (size_t)(bh * 64 + dt * 32 + l31) * TT
                            + kb * 64 + hi * 8;
            f32x16 acc = o[dt];
#pragma unroll
            for (int ks = 0; ks < 4; ++ks)
                acc = MFMA32(*(const s16x8*)(vr + ks * 16), pa[ks], acc);
            o[dt] = acc;
        }
    }

    // write O^T: lane q = qg, d = dt*32 + (reg&3)+8*(reg>>2)+4*hi
    const float inv = 1.f / lsum;
    u16* yrow = y + (size_t)(bT + qg) * 512 + hh64;
#pragma unroll
    for (int dt = 0; dt < 2; ++dt)
#pragma unroll
        for (int i = 0; i < 8; ++i) {
            const int d = dt * 32 + ((2 * i) & 3) + 8 * (i >> 1) + 4 * hi;
            *(u32*)(yrow + d) = pkbf(o[dt][2 * i] * inv, o[dt][2 * i + 1] * inv);
        }
}

// ---------------------------------------------------------------------------
// Fast LDS-tiled weight transpose fp32[K][N] -> bf16[N][K], 64x64 tiles.
// Layer launch = 768 tiles; layer-0 launch = 800 (incl. Win/Wout).
// ---------------------------------------------------------------------------
__global__ __launch_bounds__(256)
void k_wt_fast(const float* __restrict__ Wqkv, const float* __restrict__ Wo,
               const float* __restrict__ Wf1, const float* __restrict__ Wf2,
               const float* __restrict__ Win, const float* __restrict__ Wout,
               u16* __restrict__ WqkvT, u16* __restrict__ WoT,
               u16* __restrict__ Wf1T, u16* __restrict__ Wf2T,
               u16* __restrict__ WinT, u16* __restrict__ WoutT)
{
    __shared__ float T[64][65];
    const int tid = threadIdx.x;
    int id = blockIdx.x;
    const float* W; u16* Wt; int K, N;
    if (id < 192)      { W = Wqkv; Wt = WqkvT; K = 512;  N = 1536; }
    else if (id < 256) { W = Wo;   Wt = WoT;   K = 512;  N = 512;  id -= 192; }
    else if (id < 512) { W = Wf1;  Wt = Wf1T;  K = 512;  N = 2048; id -= 256; }
    else if (id < 768) { W = Wf2;  Wt = Wf2T;  K = 2048; N = 512;  id -= 512; }
    else if (id < 784) { W = Win;  Wt = WinT;  K = 128;  N = 512;  id -= 768; }
    else               { W = Wout; Wt = WoutT; K = 512;  N = 128;  id -= 784; }
    const int nt = N >> 6;
    const int ktile = id / nt, ntile = id - ktile * nt;
    const int kb = ktile * 64, nb = ntile * 64;
#pragma unroll
    for (int i = 0; i < 4; ++i) {
        const int r = i * 16 + (tid >> 4), c = (tid & 15) * 4;
        const float4 v = *(const float4*)&W[(size_t)(kb + r) * N + nb + c];
        T[r][c] = v.x; T[r][c + 1] = v.y; T[r][c + 2] = v.z; T[r][c + 3] = v.w;
    }
    __syncthreads();
    const int n = tid >> 2, k0 = (tid & 3) * 16;
    u32 pk[8];
#pragma unroll
    for (int i = 0; i < 8; ++i)
        pk[i] = pkbf(T[k0 + 2 * i][n], T[k0 + 2 * i + 1][n]);
    uint4* dst = (uint4*)(Wt + (size_t)(nb + n) * K + kb + k0);
    dst[0] = make_uint4(pk[0], pk[1], pk[2], pk[3]);
    dst[1] = make_uint4(pk[4], pk[5], pk[6], pk[7]);
}

// ---------------------------------------------------------------------------
// Fast LDS-tiled V transpose: big[t][1024+h*64+d] -> Vt[(bh*64+d)][t]
// 512 blocks (16 bh x 32 t-tiles), exact bf16 copy (no re-round).
// ---------------------------------------------------------------------------
__global__ __launch_bounds__(256)
void k_vt_fast(const u16* __restrict__ big, u16* __restrict__ Vt)
{
    __shared__ u16 T[64][66];
    const int tid = threadIdx.x;
    const int bhh = blockIdx.x >> 5, tt = blockIdx.x & 31;
    const int b = bhh >> 3, hh = bhh & 7;
#pragma unroll
    for (int i = 0; i < 2; ++i) {
        const int t = i * 32 + (tid >> 3), d0 = (tid & 7) * 8;
        const u16* src = big + (size_t)(b * TT + tt * 64 + t) * 1536 + 1024 + hh * 64 + d0;
        s16x8 v = *(const s16x8*)src;
        u32x4 u = __builtin_bit_cast(u32x4, v);
        u32* dst = (u32*)&T[t][d0];
        dst[0] = u[0]; dst[1] = u[1]; dst[2] = u[2]; dst[3] = u[3];
    }
    __syncthreads();
    const int d = tid >> 2, t0 = (tid & 3) * 16;
    u32 pk[8];
#pragma unroll
    for (int i = 0; i < 8; ++i)
        pk[i] = (u32)T[t0 + 2 * i][d] | ((u32)T[t0 + 2 * i + 1][d] << 16);
    uint4* dst = (uint4*)(Vt + (size_t)(bhh * 64 + d) * TT + tt * 64 + t0);
    dst[0] = make_uint4(pk[0], pk[1], pk[2], pk[3]);
    dst[1] = make_uint4(pk[4], pk[5], pk[6], pk[7]);
}

// x fp32 -> bf16 (8 elems/thread)
__global__ __launch_bounds__(256)
void k_f2b(const float* __restrict__ x, u16* __restrict__ xb)
{
    const int g = blockIdx.x * 256 + threadIdx.x;
    const float4* s = (const float4*)(x + (size_t)g * 8);
    float4 a = s[0], c = s[1];
    u32 pk[4] = {
        (u32)f2b(a.x) | ((u32)f2b(a.y) << 16), (u32)f2b(a.z) | ((u32)f2b(a.w) << 16),
        (u32)f2b(c.x) | ((u32)f2b(c.y) << 16), (u32)f2b(c.z) | ((u32)f2b(c.w) << 16)};
    *(uint4*)(xb + (size_t)g * 8) = make_uint4(pk[0], pk[1], pk[2], pk[3]);
}

// ---------------------------------------------------------------------------
extern "C" void kernel_launch(void* const* d_in, const int* in_sizes, int n_in,
                              void* d_out, int out_size, void* d_ws, size_t ws_size,
                              hipStream_t stream)
{
    const float* x    = (const float*)d_in[0];
    const float* Win  = (const float*)d_in[1];
    const float* bin_ = (const float*)d_in[2];
    const float* Wqkv = (const float*)d_in[3];
    const float* bqkv = (const float*)d_in[4];
    const float* Wo   = (const float*)d_in[5];
    const float* bo   = (const float*)d_in[6];
    const float* ln1g = (const float*)d_in[7];
    const float* ln1b = (const float*)d_in[8];
    const float* Wf1  = (const float*)d_in[9];
    const float* bf1  = (const float*)d_in[10];
    const float* Wf2  = (const float*)d_in[11];
    const float* bf2  = (const float*)d_in[12];
    const float* ln2g = (const float*)d_in[13];
    const float* ln2b = (const float*)d_in[14];
    const float* lnfg = (const float*)d_in[15];
    const float* lnfb = (const float*)d_in[16];
    const float* Wout = (const float*)d_in[17];
    const float* bout = (const float*)d_in[18];
    float* out = (float*)d_out;

    const int M = 4096;
    char* ws = (char*)d_ws;
    float* h    = (float*)(ws + 0);                 //  8,388,608  fp32 residual
    u16*   y    = (u16*)(ws + 8388608);             //  4,194,304  bf16 LN/attn out
    u16*   big  = (u16*)(ws + 12582912);            // 16,777,216  bf16 qkv/ff1
    u16*   Vt   = big + (size_t)4096 * 1536;        //  tail of big (4 MB)
    u16*   xb   = big;                              //  aliased: only used pre-layer0
    u16*   WinT  = (u16*)(ws + 29360128);
    u16*   WoutT = (u16*)(ws + 29491200);
    u16*   WqkvT = (u16*)(ws + 29622272);
    u16*   WoT   = (u16*)(ws + 31195136);
    u16*   Wf1T  = (u16*)(ws + 31719424);
    u16*   Wf2T  = (u16*)(ws + 33816576);

    dim3 blk(256);

    k_f2b<<<256, blk, 0, stream>>>(x, xb);

    for (int lyr = 0; lyr < 4; ++lyr) {
        k_wt_fast<<<(lyr == 0) ? 800 : 768, blk, 0, stream>>>(
            Wqkv + (size_t)lyr * 512 * 1536, Wo + (size_t)lyr * 512 * 512,
            Wf1 + (size_t)lyr * 512 * 2048, Wf2 + (size_t)lyr * 2048 * 512,
            Win, Wout, WqkvT, WoT, Wf1T, Wf2T, WinT, WoutT);
        if (lyr == 0) {
            // input projection + sinusoidal PE -> h (fp32); xb aliases big
            k_gemm_mfma<EPI_PE, 64><<<dim3(4, 64), blk, 0, stream>>>(
                xb, WinT, bin_, nullptr, h, M, 512, 128);
        }
        k_ln<<<1024, blk, 0, stream>>>(h, ln1g + lyr * 512, ln1b + lyr * 512, y);
        k_gemm_mfma<EPI_BF16, 128><<<dim3(12, 32), blk, 0, stream>>>(
            y, WqkvT, bqkv + lyr * 1536, nullptr, big, M, 1536, 512);
        k_vt_fast<<<512, blk, 0, stream>>>(big, Vt);
        k_attn<<<1024, dim3(64), 0, stream>>>(big, Vt, y);
        k_gemm_mfma<EPI_RES, 64><<<dim3(4, 64), blk, 0, stream>>>(
            y, WoT, bo + lyr * 512, h, h, M, 512, 512);
        k_ln<<<1024, blk, 0, stream>>>(h, ln2g + lyr * 512, ln2b + lyr * 512, y);
        k_gemm_mfma<EPI_GELU, 128><<<dim3(16, 32), blk, 0, stream>>>(
            y, Wf1T, bf1 + lyr * 2048, nullptr, big, M, 2048, 512);
        k_gemm_mfma<EPI_RES, 64><<<dim3(4, 64), blk, 0, stream>>>(
            big, Wf2T, bf2 + lyr * 512, h, h, M, 512, 2048);
    }

    k_ln<<<1024, blk, 0, stream>>>(h, lnfg, lnfb, y);
    k_gemm_mfma<EPI_OUTF, 64><<<dim3(1, 64), blk, 0, stream>>>(
        y, WoutT, bout, nullptr, out, M, 128, 512);
}

// Round 5
// 565.245 us; speedup vs baseline: 7.2852x; 1.1377x over previous
//
#include <hip/hip_runtime.h>
#include <math.h>
#include <type_traits>
#include <utility>

#define TT 2048
typedef unsigned short u16;
typedef unsigned int u32;
typedef float f32x4 __attribute__((ext_vector_type(4)));
typedef float f32x16 __attribute__((ext_vector_type(16)));
typedef short s16x8 __attribute__((ext_vector_type(8)));
typedef __bf16 bf16x8 __attribute__((ext_vector_type(8)));
typedef __bf16 bf16x2 __attribute__((ext_vector_type(2)));
typedef u32 u32x4 __attribute__((ext_vector_type(4)));

enum { EPI_PE = 0, EPI_BF16 = 1, EPI_RES = 2, EPI_GELU = 3, EPI_OUTF = 4 };

// ---- MFMA wrappers: handle either builtin signature (v8i16 or v8bf16) ----
template<typename V, typename = void> struct mfma_takes : std::false_type {};
template<typename V> struct mfma_takes<V, std::void_t<decltype(
    __builtin_amdgcn_mfma_f32_16x16x32_bf16(std::declval<V>(), std::declval<V>(),
                                            std::declval<f32x4>(), 0, 0, 0))>>
    : std::true_type {};

template<typename VA>
__device__ __forceinline__ f32x4 MFMA_t(VA a, VA b, f32x4 c) {
    if constexpr (mfma_takes<VA>::value) {
        return __builtin_amdgcn_mfma_f32_16x16x32_bf16(a, b, c, 0, 0, 0);
    } else {
        return __builtin_amdgcn_mfma_f32_16x16x32_bf16(
            __builtin_bit_cast(bf16x8, a), __builtin_bit_cast(bf16x8, b), c, 0, 0, 0);
    }
}

template<typename V, typename = void> struct mfma32_takes : std::false_type {};
template<typename V> struct mfma32_takes<V, std::void_t<decltype(
    __builtin_amdgcn_mfma_f32_32x32x16_bf16(std::declval<V>(), std::declval<V>(),
                                            std::declval<f32x16>(), 0, 0, 0))>>
    : std::true_type {};

template<typename VA>
__device__ __forceinline__ f32x16 MFMA32(VA a, VA b, f32x16 c) {
    if constexpr (mfma32_takes<VA>::value) {
        return __builtin_amdgcn_mfma_f32_32x32x16_bf16(a, b, c, 0, 0, 0);
    } else {
        return __builtin_amdgcn_mfma_f32_32x32x16_bf16(
            __builtin_bit_cast(bf16x8, a), __builtin_bit_cast(bf16x8, b), c, 0, 0, 0);
    }
}

// fp32 -> bf16 RNE
__device__ __forceinline__ u16 f2b(float f) {
    u32 u = __float_as_uint(f);
    return (u16)((u + 0x7FFFu + ((u >> 16) & 1u)) >> 16);
}

__device__ __forceinline__ u32 pkbf(float a, float b) {
    bf16x2 t; t[0] = (__bf16)a; t[1] = (__bf16)b;
    return __builtin_bit_cast(u32, t);
}

// async global->LDS, 16B per lane; LDS dest = uniform base + lane*16
__device__ __forceinline__ void gload16(const void* g, void* lds_base, int lds_byte_off) {
    __builtin_amdgcn_global_load_lds(
        (const __attribute__((address_space(1))) void*)g,
        (__attribute__((address_space(3))) void*)((char*)lds_base + lds_byte_off),
        16, 0, 0);
}

// ---------------------------------------------------------------------------
// bf16 MFMA GEMM: C[M,N] = A[M,K](bf16 rm) @ Bt[N,K]^T (bf16) + bias
// Tile TM x TN (each 64 or 128), BK=32, 4 waves (2x2); wave = TM/2 x TN/2.
// Smaller tiles -> more blocks/CU -> wave-level latency overlap (m114).
// ---------------------------------------------------------------------------
template<int EPI, int TM, int TN>
__global__ __launch_bounds__(256)
void k_gemm_mfma(const u16* __restrict__ A, const u16* __restrict__ Bt,
                 const float* __restrict__ bias, const float* __restrict__ Rf,
                 void* __restrict__ Cout, int M, int N, int K)
{
    constexpr int MF = TM / 32;                 // m-frags per wave
    constexpr int NF = TN / 32;                 // n-frags per wave
    __shared__ __attribute__((aligned(16))) u16 As[TM * 32];
    __shared__ __attribute__((aligned(16))) u16 Bs[TN * 32];
    const int tid = threadIdx.x;
    const int l = tid & 63, wv = tid >> 6;
    const int l15 = l & 15, lg = l >> 4;
    const int wr = wv >> 1, wc = wv & 1;
    const int row0 = blockIdx.y * TM, col0 = blockIdx.x * TN;

    f32x4 acc[MF][NF];
#pragma unroll
    for (int m = 0; m < MF; ++m)
#pragma unroll
        for (int n = 0; n < NF; ++n) acc[m][n] = (f32x4){0.f, 0.f, 0.f, 0.f};

    for (int kt = 0; kt < K; kt += 32) {
#pragma unroll
        for (int i = 0; i < TM / 64; ++i) {          // A: TM*4 chunks of 16B
            const int u = i * 256 + wv * 64 + l;
            const int ar = u >> 2, ac = u & 3;
            const int sc = (ac ^ ((ar >> 1) & 3)) << 3;
            const int off = __builtin_amdgcn_readfirstlane((i * 256 + wv * 64) * 16);
            gload16(A + (size_t)(row0 + ar) * K + kt + sc, As, off);
        }
#pragma unroll
        for (int i = 0; i < TN / 64; ++i) {          // B: TN*4 chunks
            const int u = i * 256 + wv * 64 + l;
            const int ar = u >> 2, ac = u & 3;
            const int sc = (ac ^ ((ar >> 1) & 3)) << 3;
            const int off = __builtin_amdgcn_readfirstlane((i * 256 + wv * 64) * 16);
            gload16(Bt + (size_t)(col0 + ar) * K + kt + sc, Bs, off);
        }
        __syncthreads();
        s16x8 af[MF], bf[NF];
#pragma unroll
        for (int m = 0; m < MF; ++m) {
            const int r = wr * (TM / 2) + m * 16 + l15;
            af[m] = *(const s16x8*)(As + r * 32 + ((lg ^ ((r >> 1) & 3)) << 3));
        }
#pragma unroll
        for (int n = 0; n < NF; ++n) {
            const int r = wc * (TN / 2) + n * 16 + l15;
            bf[n] = *(const s16x8*)(Bs + r * 32 + ((lg ^ ((r >> 1) & 3)) << 3));
        }
#pragma unroll
        for (int m = 0; m < MF; ++m)
#pragma unroll
            for (int n = 0; n < NF; ++n) acc[m][n] = MFMA_t(af[m], bf[n], acc[m][n]);
        __syncthreads();
    }

#pragma unroll
    for (int m = 0; m < MF; ++m)
#pragma unroll
        for (int rg = 0; rg < 4; ++rg) {
            const int row = row0 + wr * (TM / 2) + m * 16 + lg * 4 + rg;
#pragma unroll
            for (int n = 0; n < NF; ++n) {
                const int col = col0 + wc * (TN / 2) + n * 16 + l15;
                float v = acc[m][n][rg] + bias[col];
                const size_t idx = (size_t)row * N + col;
                if constexpr (EPI == EPI_PE) {
                    const int t = row & (TT - 1);
                    const float freq = __expf(-(float)(col & ~1) * 0.017988946039015984f);
                    const float ang = (float)t * freq;
                    v += (col & 1) ? cosf(ang) : sinf(ang);
                    ((float*)Cout)[idx] = v;
                } else if constexpr (EPI == EPI_BF16) {
                    ((u16*)Cout)[idx] = f2b(v);
                } else if constexpr (EPI == EPI_GELU) {
                    v = 0.5f * v * (1.f + erff(v * 0.7071067811865475f));
                    ((u16*)Cout)[idx] = f2b(v);
                } else if constexpr (EPI == EPI_RES) {
                    ((float*)Cout)[idx] = Rf[idx] + v;
                } else {
                    ((float*)Cout)[idx] = v;
                }
            }
        }
}

// ---------------------------------------------------------------------------
// LayerNorm D=512: h(fp32) -> y(bf16). One wave per row.
// ---------------------------------------------------------------------------
__global__ __launch_bounds__(256)
void k_ln(const float* __restrict__ X, const float* __restrict__ g,
          const float* __restrict__ b, u16* __restrict__ Y)
{
    const int lane = threadIdx.x & 63;
    const int row = blockIdx.x * 4 + (threadIdx.x >> 6);
    const float* x = X + (size_t)row * 512 + lane * 8;

    float4 v0 = *(const float4*)x;
    float4 v1 = *(const float4*)(x + 4);
    float vals[8] = {v0.x, v0.y, v0.z, v0.w, v1.x, v1.y, v1.z, v1.w};

    float s = 0.f;
#pragma unroll
    for (int i = 0; i < 8; ++i) s += vals[i];
#pragma unroll
    for (int off = 32; off >= 1; off >>= 1) s += __shfl_xor(s, off);
    const float mu = s * (1.f / 512.f);

    float sq = 0.f;
#pragma unroll
    for (int i = 0; i < 8; ++i) { float d = vals[i] - mu; sq += d * d; }
#pragma unroll
    for (int off = 32; off >= 1; off >>= 1) sq += __shfl_xor(sq, off);
    const float rs = rsqrtf(sq * (1.f / 512.f) + 1e-5f);

    const float* gp = g + lane * 8;
    const float* bp = b + lane * 8;
    float4 g0 = *(const float4*)gp, g1 = *(const float4*)(gp + 4);
    float4 b0 = *(const float4*)bp, b1 = *(const float4*)(bp + 4);
    float ga[8] = {g0.x, g0.y, g0.z, g0.w, g1.x, g1.y, g1.z, g1.w};
    float bb[8] = {b0.x, b0.y, b0.z, b0.w, b1.x, b1.y, b1.z, b1.w};

    u32 pk[4];
#pragma unroll
    for (int i = 0; i < 4; ++i) {
        float a0 = (vals[2 * i]     - mu) * rs * ga[2 * i]     + bb[2 * i];
        float a1 = (vals[2 * i + 1] - mu) * rs * ga[2 * i + 1] + bb[2 * i + 1];
        pk[i] = (u32)f2b(a0) | ((u32)f2b(a1) << 16);
    }
    *(uint4*)(Y + (size_t)row * 512 + lane * 8) = make_uint4(pk[0], pk[1], pk[2], pk[3]);
}

// ---------------------------------------------------------------------------
// Causal flash attention, in-block split-KV. 1024 blocks x 256 thr (4 waves).
// Block = (bh, 32-row q-tile) via XCD swizzle + LPT (long q-tiles first).
// Wave w handles kv tiles {w, w+4, w+8, ...} of the q-tile's range with the
// LDS-free in-register pipeline (S^T=mfma32(K,Q), in-lane softmax, P repack
// via shfl_xor(32), O^T=mfma32(Vt,P)); partial (m,l,O) merged through a
// padded LDS tile after one __syncthreads. 4 waves/SIMD -> latency overlap.
// ---------------------------------------------------------------------------
__global__ __launch_bounds__(256, 4)
void k_attn(const u16* __restrict__ qkv, const u16* __restrict__ Vt, u16* __restrict__ y)
{
    __shared__ float Om[4][32 * 65];     // [wave][q*65 + d], pad-65 rows
    __shared__ float Ml[4][32][2];       // [wave][q][{m,l}]
    const int tid = threadIdx.x;
    const int l = tid & 63, w = tid >> 6;
    const int l31 = l & 31, hi = l >> 5;
    const int bx = blockIdx.x;
    const int xcd = bx & 7, s = bx >> 3;
    const int bh = xcd * 2 + (s & 1);
    const int t_tile = 63 - (s >> 1);
    const int b = bh >> 3, hh = bh & 7;
    const int bT = b * TT, hh64 = hh * 64;

    const int qg = t_tile * 32 + l31;
    const int NT = (t_tile >> 1) + 1;    // kv tiles (64-wide) this q-tile needs

    f32x16 o[2] = {};
    float m = -1e30f, lsum = 0.f;

    if (w < NT) {
        // Q B-frags
        s16x8 qf[4];
        {
            const u16* qsrc = qkv + (size_t)(bT + qg) * 1536 + hh64 + hi * 8;
#pragma unroll
            for (int dk = 0; dk < 4; ++dk) qf[dk] = *(const s16x8*)(qsrc + dk * 16);
        }

        for (int g = w; g < NT; g += 4) {
            // load K tile frags straight from L2
            s16x8 kf[8];
#pragma unroll
            for (int nb = 0; nb < 2; ++nb) {
                const u16* kr = qkv + (size_t)(bT + g * 64 + nb * 32 + l31) * 1536
                                + 512 + hh64 + hi * 8;
#pragma unroll
                for (int dk = 0; dk < 4; ++dk)
                    kf[nb * 4 + dk] = *(const s16x8*)(kr + dk * 16);
            }

            // S^T = K Q^T over d=64
            f32x16 sA[2];
#pragma unroll
            for (int nb = 0; nb < 2; ++nb) {
                f32x16 acc = {};
#pragma unroll
                for (int dk = 0; dk < 4; ++dk) acc = MFMA32(kf[nb * 4 + dk], qf[dk], acc);
                sA[nb] = acc;
            }

            // causal mask on the diagonal supertile
            if (g == NT - 1) {
                const int kvb = g * 64, hi4 = hi * 4;
#pragma unroll
                for (int nb = 0; nb < 2; ++nb)
#pragma unroll
                    for (int r = 0; r < 16; ++r) {
                        const int kv = kvb + nb * 32 + (r & 3) + 8 * (r >> 2) + hi4;
                        sA[nb][r] = (kv > qg) ? -1e30f : sA[nb][r];
                    }
            }

            // online softmax (scale 1/8 folded into exp)
            float tmp[16];
#pragma unroll
            for (int r = 0; r < 16; ++r) tmp[r] = fmaxf(sA[0][r], sA[1][r]);
#pragma unroll
            for (int st = 8; st >= 1; st >>= 1)
#pragma unroll
                for (int r = 0; r < 8; ++r)
                    if (r < st) tmp[r] = fmaxf(tmp[r], tmp[r + st]);
            float mt = fmaxf(tmp[0], __shfl_xor(tmp[0], 32));
            const float mn = fmaxf(m, mt);
            const float alpha = __expf((m - mn) * 0.125f);
            m = mn;
            const float mc = -mn * 0.125f;

            float p[2][16];
            float sum[16];
#pragma unroll
            for (int r = 0; r < 16; ++r) {
                p[0][r] = __expf(fmaf(sA[0][r], 0.125f, mc));
                p[1][r] = __expf(fmaf(sA[1][r], 0.125f, mc));
                sum[r] = p[0][r] + p[1][r];
            }
#pragma unroll
            for (int st = 8; st >= 1; st >>= 1)
#pragma unroll
                for (int r = 0; r < 8; ++r)
                    if (r < st) sum[r] += sum[r + st];
            float psum = sum[0] + __shfl_xor(sum[0], 32);
            lsum = lsum * alpha + psum;
#pragma unroll
            for (int dt = 0; dt < 2; ++dt)
#pragma unroll
                for (int r = 0; r < 16; ++r) o[dt][r] *= alpha;

            // P (f32, D-layout) -> bf16 A-frags via lane<->lane+32 exchange
            u32 pk2[2][8], sw2[2][8];
#pragma unroll
            for (int nb = 0; nb < 2; ++nb)
#pragma unroll
                for (int i = 0; i < 8; ++i) {
                    pk2[nb][i] = pkbf(p[nb][2 * i], p[nb][2 * i + 1]);
                    sw2[nb][i] = __shfl_xor(pk2[nb][i], 32);
                }
            s16x8 pa[4];
#pragma unroll
            for (int nb = 0; nb < 2; ++nb)
#pragma unroll
                for (int k16 = 0; k16 < 2; ++k16) {
                    const int i0 = k16 * 4;
                    u32 w0 = hi ? sw2[nb][i0 + 2] : pk2[nb][i0 + 0];
                    u32 w1 = hi ? sw2[nb][i0 + 3] : pk2[nb][i0 + 1];
                    u32 w2 = hi ? pk2[nb][i0 + 2] : sw2[nb][i0 + 0];
                    u32 w3 = hi ? pk2[nb][i0 + 3] : sw2[nb][i0 + 1];
                    u32x4 t4 = {w0, w1, w2, w3};
                    pa[nb * 2 + k16] = __builtin_bit_cast(s16x8, t4);
                }

            // O^T += V^T P^T, V frags straight from L2
#pragma unroll
            for (int dt = 0; dt < 2; ++dt) {
                const u16* vr = Vt + (size_t)(bh * 64 + dt * 32 + l31) * TT
                                + g * 64 + hi * 8;
                f32x16 acc = o[dt];
#pragma unroll
                for (int ks = 0; ks < 4; ++ks)
                    acc = MFMA32(*(const s16x8*)(vr + ks * 16), pa[ks], acc);
                o[dt] = acc;
            }
        }
    }

    // ---- dump partials: lane q = l31, d = dt*32 + (r&3)+8*(r>>2)+4*hi
#pragma unroll
    for (int dt = 0; dt < 2; ++dt)
#pragma unroll
        for (int r = 0; r < 16; ++r) {
            const int d = dt * 32 + (r & 3) + 8 * (r >> 2) + 4 * hi;
            Om[w][l31 * 65 + d] = o[dt][r];
        }
    Ml[w][l31][0] = m;
    Ml[w][l31][1] = lsum;
    __syncthreads();

    // ---- combine: thread -> (q = tid&31, d-range (tid>>5)*8 .. +7)
    const int q = tid & 31, d0 = (tid >> 5) * 8;
    float m0 = Ml[0][q][0], m1 = Ml[1][q][0], m2 = Ml[2][q][0], m3 = Ml[3][q][0];
    const float mstar = fmaxf(fmaxf(m0, m1), fmaxf(m2, m3));
    float sc[4];
    sc[0] = __expf((m0 - mstar) * 0.125f);
    sc[1] = __expf((m1 - mstar) * 0.125f);
    sc[2] = __expf((m2 - mstar) * 0.125f);
    sc[3] = __expf((m3 - mstar) * 0.125f);
    const float lstar = sc[0] * Ml[0][q][1] + sc[1] * Ml[1][q][1]
                      + sc[2] * Ml[2][q][1] + sc[3] * Ml[3][q][1];
    float ov[8];
#pragma unroll
    for (int j = 0; j < 8; ++j) ov[j] = 0.f;
#pragma unroll
    for (int ww = 0; ww < 4; ++ww) {
        const float scw = sc[ww];
        const float* src = &Om[ww][q * 65 + d0];
#pragma unroll
        for (int j = 0; j < 8; ++j) ov[j] = fmaf(scw, src[j], ov[j]);
    }
    const float inv = 1.f / lstar;
    u32 pk[4];
#pragma unroll
    for (int i = 0; i < 4; ++i) pk[i] = pkbf(ov[2 * i] * inv, ov[2 * i + 1] * inv);
    u16* yp = y + (size_t)(bT + t_tile * 32 + q) * 512 + hh64 + d0;
    *(uint4*)yp = make_uint4(pk[0], pk[1], pk[2], pk[3]);
}

// ---------------------------------------------------------------------------
// Fast LDS-tiled weight transpose fp32[K][N] -> bf16[N][K], 64x64 tiles.
// ---------------------------------------------------------------------------
__global__ __launch_bounds__(256)
void k_wt_fast(const float* __restrict__ Wqkv, const float* __restrict__ Wo,
               const float* __restrict__ Wf1, const float* __restrict__ Wf2,
               const float* __restrict__ Win, const float* __restrict__ Wout,
               u16* __restrict__ WqkvT, u16* __restrict__ WoT,
               u16* __restrict__ Wf1T, u16* __restrict__ Wf2T,
               u16* __restrict__ WinT, u16* __restrict__ WoutT)
{
    __shared__ float T[64][65];
    const int tid = threadIdx.x;
    int id = blockIdx.x;
    const float* W; u16* Wt; int K, N;
    if (id < 192)      { W = Wqkv; Wt = WqkvT; K = 512;  N = 1536; }
    else if (id < 256) { W = Wo;   Wt = WoT;   K = 512;  N = 512;  id -= 192; }
    else if (id < 512) { W = Wf1;  Wt = Wf1T;  K = 512;  N = 2048; id -= 256; }
    else if (id < 768) { W = Wf2;  Wt = Wf2T;  K = 2048; N = 512;  id -= 512; }
    else if (id < 784) { W = Win;  Wt = WinT;  K = 128;  N = 512;  id -= 768; }
    else               { W = Wout; Wt = WoutT; K = 512;  N = 128;  id -= 784; }
    const int nt = N >> 6;
    const int ktile = id / nt, ntile = id - ktile * nt;
    const int kb = ktile * 64, nb = ntile * 64;
#pragma unroll
    for (int i = 0; i < 4; ++i) {
        const int r = i * 16 + (tid >> 4), c = (tid & 15) * 4;
        const float4 v = *(const float4*)&W[(size_t)(kb + r) * N + nb + c];
        T[r][c] = v.x; T[r][c + 1] = v.y; T[r][c + 2] = v.z; T[r][c + 3] = v.w;
    }
    __syncthreads();
    const int n = tid >> 2, k0 = (tid & 3) * 16;
    u32 pk[8];
#pragma unroll
    for (int i = 0; i < 8; ++i)
        pk[i] = pkbf(T[k0 + 2 * i][n], T[k0 + 2 * i + 1][n]);
    uint4* dst = (uint4*)(Wt + (size_t)(nb + n) * K + kb + k0);
    dst[0] = make_uint4(pk[0], pk[1], pk[2], pk[3]);
    dst[1] = make_uint4(pk[4], pk[5], pk[6], pk[7]);
}

// ---------------------------------------------------------------------------
// Fast LDS-tiled V transpose: big[t][1024+h*64+d] -> Vt[(bh*64+d)][t]
// ---------------------------------------------------------------------------
__global__ __launch_bounds__(256)
void k_vt_fast(const u16* __restrict__ big, u16* __restrict__ Vt)
{
    __shared__ u16 T[64][66];
    const int tid = threadIdx.x;
    const int bhh = blockIdx.x >> 5, tt = blockIdx.x & 31;
    const int b = bhh >> 3, hh = bhh & 7;
#pragma unroll
    for (int i = 0; i < 2; ++i) {
        const int t = i * 32 + (tid >> 3), d0 = (tid & 7) * 8;
        const u16* src = big + (size_t)(b * TT + tt * 64 + t) * 1536 + 1024 + hh * 64 + d0;
        s16x8 v = *(const s16x8*)src;
        u32x4 u = __builtin_bit_cast(u32x4, v);
        u32* dst = (u32*)&T[t][d0];
        dst[0] = u[0]; dst[1] = u[1]; dst[2] = u[2]; dst[3] = u[3];
    }
    __syncthreads();
    const int d = tid >> 2, t0 = (tid & 3) * 16;
    u32 pk[8];
#pragma unroll
    for (int i = 0; i < 8; ++i)
        pk[i] = (u32)T[t0 + 2 * i][d] | ((u32)T[t0 + 2 * i + 1][d] << 16);
    uint4* dst = (uint4*)(Vt + (size_t)(bhh * 64 + d) * TT + tt * 64 + t0);
    dst[0] = make_uint4(pk[0], pk[1], pk[2], pk[3]);
    dst[1] = make_uint4(pk[4], pk[5], pk[6], pk[7]);
}

// x fp32 -> bf16 (8 elems/thread)
__global__ __launch_bounds__(256)
void k_f2b(const float* __restrict__ x, u16* __restrict__ xb)
{
    const int g = blockIdx.x * 256 + threadIdx.x;
    const float4* s = (const float4*)(x + (size_t)g * 8);
    float4 a = s[0], c = s[1];
    u32 pk[4] = {
        (u32)f2b(a.x) | ((u32)f2b(a.y) << 16), (u32)f2b(a.z) | ((u32)f2b(a.w) << 16),
        (u32)f2b(c.x) | ((u32)f2b(c.y) << 16), (u32)f2b(c.z) | ((u32)f2b(c.w) << 16)};
    *(uint4*)(xb + (size_t)g * 8) = make_uint4(pk[0], pk[1], pk[2], pk[3]);
}

// ---------------------------------------------------------------------------
extern "C" void kernel_launch(void* const* d_in, const int* in_sizes, int n_in,
                              void* d_out, int out_size, void* d_ws, size_t ws_size,
                              hipStream_t stream)
{
    const float* x    = (const float*)d_in[0];
    const float* Win  = (const float*)d_in[1];
    const float* bin_ = (const float*)d_in[2];
    const float* Wqkv = (const float*)d_in[3];
    const float* bqkv = (const float*)d_in[4];
    const float* Wo   = (const float*)d_in[5];
    const float* bo   = (const float*)d_in[6];
    const float* ln1g = (const float*)d_in[7];
    const float* ln1b = (const float*)d_in[8];
    const float* Wf1  = (const float*)d_in[9];
    const float* bf1  = (const float*)d_in[10];
    const float* Wf2  = (const float*)d_in[11];
    const float* bf2  = (const float*)d_in[12];
    const float* ln2g = (const float*)d_in[13];
    const float* ln2b = (const float*)d_in[14];
    const float* lnfg = (const float*)d_in[15];
    const float* lnfb = (const float*)d_in[16];
    const float* Wout = (const float*)d_in[17];
    const float* bout = (const float*)d_in[18];
    float* out = (float*)d_out;

    const int M = 4096;
    char* ws = (char*)d_ws;
    float* h    = (float*)(ws + 0);                 //  8,388,608  fp32 residual
    u16*   y    = (u16*)(ws + 8388608);             //  4,194,304  bf16 LN/attn out
    u16*   big  = (u16*)(ws + 12582912);            // 16,777,216  bf16 qkv/ff1
    u16*   Vt   = big + (size_t)4096 * 1536;        //  tail of big (4 MB)
    u16*   xb   = big;                              //  aliased: only used pre-layer0
    u16*   WinT  = (u16*)(ws + 29360128);
    u16*   WoutT = (u16*)(ws + 29491200);
    u16*   WqkvT = (u16*)(ws + 29622272);
    u16*   WoT   = (u16*)(ws + 31195136);
    u16*   Wf1T  = (u16*)(ws + 31719424);
    u16*   Wf2T  = (u16*)(ws + 33816576);

    dim3 blk(256);

    k_f2b<<<256, blk, 0, stream>>>(x, xb);

    for (int lyr = 0; lyr < 4; ++lyr) {
        k_wt_fast<<<(lyr == 0) ? 800 : 768, blk, 0, stream>>>(
            Wqkv + (size_t)lyr * 512 * 1536, Wo + (size_t)lyr * 512 * 512,
            Wf1 + (size_t)lyr * 512 * 2048, Wf2 + (size_t)lyr * 2048 * 512,
            Win, Wout, WqkvT, WoT, Wf1T, Wf2T, WinT, WoutT);
        if (lyr == 0) {
            // input projection + sinusoidal PE -> h (fp32); xb aliases big
            k_gemm_mfma<EPI_PE, 64, 64><<<dim3(8, 64), blk, 0, stream>>>(
                xb, WinT, bin_, nullptr, h, M, 512, 128);
        }
        k_ln<<<1024, blk, 0, stream>>>(h, ln1g + lyr * 512, ln1b + lyr * 512, y);
        k_gemm_mfma<EPI_BF16, 64, 128><<<dim3(12, 64), blk, 0, stream>>>(
            y, WqkvT, bqkv + lyr * 1536, nullptr, big, M, 1536, 512);
        k_vt_fast<<<512, blk, 0, stream>>>(big, Vt);
        k_attn<<<1024, blk, 0, stream>>>(big, Vt, y);
        k_gemm_mfma<EPI_RES, 64, 64><<<dim3(8, 64), blk, 0, stream>>>(
            y, WoT, bo + lyr * 512, h, h, M, 512, 512);
        k_ln<<<1024, blk, 0, stream>>>(h, ln2g + lyr * 512, ln2b + lyr * 512, y);
        k_gemm_mfma<EPI_GELU, 64, 128><<<dim3(16, 64), blk, 0, stream>>>(
            y, Wf1T, bf1 + lyr * 2048, nullptr, big, M, 2048, 512);
        k_gemm_mfma<EPI_RES, 64, 64><<<dim3(8, 64), blk, 0, stream>>>(
            big, Wf2T, bf2 + lyr * 512, h, h, M, 512, 2048);
    }

    k_ln<<<1024, blk, 0, stream>>>(h, lnfg, lnfb, y);
    k_gemm_mfma<EPI_OUTF, 64, 64><<<dim3(2, 64), blk, 0, stream>>>(
        y, WoutT, bout, nullptr, out, M, 128, 512);
}

// Round 6
// 486.519 us; speedup vs baseline: 8.4640x; 1.1618x over previous
//
#include <hip/hip_runtime.h>
#include <math.h>
#include <type_traits>
#include <utility>

#define TT 2048
typedef unsigned short u16;
typedef unsigned int u32;
typedef float f32x4 __attribute__((ext_vector_type(4)));
typedef float f32x16 __attribute__((ext_vector_type(16)));
typedef short s16x8 __attribute__((ext_vector_type(8)));
typedef __bf16 bf16x8 __attribute__((ext_vector_type(8)));
typedef __bf16 bf16x2 __attribute__((ext_vector_type(2)));
typedef u32 u32x4 __attribute__((ext_vector_type(4)));

enum { EPI_PE = 0, EPI_BF16 = 1, EPI_RES = 2, EPI_GELU = 3, EPI_OUTF = 4 };

// ---- MFMA wrappers: handle either builtin signature (v8i16 or v8bf16) ----
template<typename V, typename = void> struct mfma_takes : std::false_type {};
template<typename V> struct mfma_takes<V, std::void_t<decltype(
    __builtin_amdgcn_mfma_f32_16x16x32_bf16(std::declval<V>(), std::declval<V>(),
                                            std::declval<f32x4>(), 0, 0, 0))>>
    : std::true_type {};

template<typename VA>
__device__ __forceinline__ f32x4 MFMA_t(VA a, VA b, f32x4 c) {
    if constexpr (mfma_takes<VA>::value) {
        return __builtin_amdgcn_mfma_f32_16x16x32_bf16(a, b, c, 0, 0, 0);
    } else {
        return __builtin_amdgcn_mfma_f32_16x16x32_bf16(
            __builtin_bit_cast(bf16x8, a), __builtin_bit_cast(bf16x8, b), c, 0, 0, 0);
    }
}

template<typename V, typename = void> struct mfma32_takes : std::false_type {};
template<typename V> struct mfma32_takes<V, std::void_t<decltype(
    __builtin_amdgcn_mfma_f32_32x32x16_bf16(std::declval<V>(), std::declval<V>(),
                                            std::declval<f32x16>(), 0, 0, 0))>>
    : std::true_type {};

template<typename VA>
__device__ __forceinline__ f32x16 MFMA32(VA a, VA b, f32x16 c) {
    if constexpr (mfma32_takes<VA>::value) {
        return __builtin_amdgcn_mfma_f32_32x32x16_bf16(a, b, c, 0, 0, 0);
    } else {
        return __builtin_amdgcn_mfma_f32_32x32x16_bf16(
            __builtin_bit_cast(bf16x8, a), __builtin_bit_cast(bf16x8, b), c, 0, 0, 0);
    }
}

// fp32 -> bf16 RNE
__device__ __forceinline__ u16 f2b(float f) {
    u32 u = __float_as_uint(f);
    return (u16)((u + 0x7FFFu + ((u >> 16) & 1u)) >> 16);
}

__device__ __forceinline__ u32 pkbf(float a, float b) {
    bf16x2 t; t[0] = (__bf16)a; t[1] = (__bf16)b;
    return __builtin_bit_cast(u32, t);
}

// async global->LDS, 16B per lane; LDS dest = uniform base + lane*16
__device__ __forceinline__ void gload16(const void* g, void* lds_base, int lds_byte_off) {
    __builtin_amdgcn_global_load_lds(
        (const __attribute__((address_space(1))) void*)g,
        (__attribute__((address_space(3))) void*)((char*)lds_base + lds_byte_off),
        16, 0, 0);
}

// ---------------------------------------------------------------------------
// bf16 MFMA GEMM: C[M,N] = A[M,K](bf16 rm) @ Bt[N,K]^T (bf16) + bias
// Tile TM x TN, BK=64 (8 barriers for K=512), 4 waves (2x2).
// LDS rows 64 u16 = 8 chunks of 16B, chunk c stored at slot c^(r&7):
// b128 frag reads spread 8 lanes/bank-quad (optimal), staging keeps rows
// contiguous (full-line coalescing with intra-row chunk permute).
// ---------------------------------------------------------------------------
template<int EPI, int TM, int TN>
__global__ __launch_bounds__(256)
void k_gemm_mfma(const u16* __restrict__ A, const u16* __restrict__ Bt,
                 const float* __restrict__ bias, const float* __restrict__ Rf,
                 void* __restrict__ Cout, int M, int N, int K)
{
    constexpr int MF = TM / 32;                 // m-frags per wave
    constexpr int NF = TN / 32;                 // n-frags per wave
    __shared__ __attribute__((aligned(16))) u16 As[TM * 64];
    __shared__ __attribute__((aligned(16))) u16 Bs[TN * 64];
    const int tid = threadIdx.x;
    const int l = tid & 63, wv = tid >> 6;
    const int l15 = l & 15, lg = l >> 4;
    const int wr = wv >> 1, wc = wv & 1;
    const int row0 = blockIdx.y * TM, col0 = blockIdx.x * TN;

    f32x4 acc[MF][NF];
#pragma unroll
    for (int m = 0; m < MF; ++m)
#pragma unroll
        for (int n = 0; n < NF; ++n) acc[m][n] = (f32x4){0.f, 0.f, 0.f, 0.f};

    for (int kt = 0; kt < K; kt += 64) {
#pragma unroll
        for (int i = 0; i < TM / 32; ++i) {          // A: TM*8 chunks of 16B
            const int u = i * 256 + wv * 64 + l;
            const int ar = u >> 3, ac = u & 7;
            const int sc = (ac ^ (ar & 7)) << 3;     // source chunk *8 elems
            const int off = __builtin_amdgcn_readfirstlane((i * 256 + wv * 64) * 16);
            gload16(A + (size_t)(row0 + ar) * K + kt + sc, As, off);
        }
#pragma unroll
        for (int i = 0; i < TN / 32; ++i) {          // B: TN*8 chunks
            const int u = i * 256 + wv * 64 + l;
            const int ar = u >> 3, ac = u & 7;
            const int sc = (ac ^ (ar & 7)) << 3;
            const int off = __builtin_amdgcn_readfirstlane((i * 256 + wv * 64) * 16);
            gload16(Bt + (size_t)(col0 + ar) * K + kt + sc, Bs, off);
        }
        __syncthreads();
        s16x8 af[MF][2], bf[NF][2];
#pragma unroll
        for (int m = 0; m < MF; ++m) {
            const int r = wr * (TM / 2) + m * 16 + l15;
#pragma unroll
            for (int s = 0; s < 2; ++s)
                af[m][s] = *(const s16x8*)(As + r * 64 + (((s * 4 + lg) ^ (r & 7)) << 3));
        }
#pragma unroll
        for (int n = 0; n < NF; ++n) {
            const int r = wc * (TN / 2) + n * 16 + l15;
#pragma unroll
            for (int s = 0; s < 2; ++s)
                bf[n][s] = *(const s16x8*)(Bs + r * 64 + (((s * 4 + lg) ^ (r & 7)) << 3));
        }
#pragma unroll
        for (int s = 0; s < 2; ++s)
#pragma unroll
            for (int m = 0; m < MF; ++m)
#pragma unroll
                for (int n = 0; n < NF; ++n)
                    acc[m][n] = MFMA_t(af[m][s], bf[n][s], acc[m][n]);
        __syncthreads();
    }

#pragma unroll
    for (int m = 0; m < MF; ++m)
#pragma unroll
        for (int rg = 0; rg < 4; ++rg) {
            const int row = row0 + wr * (TM / 2) + m * 16 + lg * 4 + rg;
#pragma unroll
            for (int n = 0; n < NF; ++n) {
                const int col = col0 + wc * (TN / 2) + n * 16 + l15;
                float v = acc[m][n][rg] + bias[col];
                const size_t idx = (size_t)row * N + col;
                if constexpr (EPI == EPI_PE) {
                    const int t = row & (TT - 1);
                    const float freq = __expf(-(float)(col & ~1) * 0.017988946039015984f);
                    const float ang = (float)t * freq;
                    v += (col & 1) ? cosf(ang) : sinf(ang);
                    ((float*)Cout)[idx] = v;
                } else if constexpr (EPI == EPI_BF16) {
                    ((u16*)Cout)[idx] = f2b(v);
                } else if constexpr (EPI == EPI_GELU) {
                    v = 0.5f * v * (1.f + erff(v * 0.7071067811865475f));
                    ((u16*)Cout)[idx] = f2b(v);
                } else if constexpr (EPI == EPI_RES) {
                    ((float*)Cout)[idx] = Rf[idx] + v;
                } else {
                    ((float*)Cout)[idx] = v;
                }
            }
        }
}

// ---------------------------------------------------------------------------
// LayerNorm D=512: h(fp32) -> y(bf16). One wave per row.
// ---------------------------------------------------------------------------
__global__ __launch_bounds__(256)
void k_ln(const float* __restrict__ X, const float* __restrict__ g,
          const float* __restrict__ b, u16* __restrict__ Y)
{
    const int lane = threadIdx.x & 63;
    const int row = blockIdx.x * 4 + (threadIdx.x >> 6);
    const float* x = X + (size_t)row * 512 + lane * 8;

    float4 v0 = *(const float4*)x;
    float4 v1 = *(const float4*)(x + 4);
    float vals[8] = {v0.x, v0.y, v0.z, v0.w, v1.x, v1.y, v1.z, v1.w};

    float s = 0.f;
#pragma unroll
    for (int i = 0; i < 8; ++i) s += vals[i];
#pragma unroll
    for (int off = 32; off >= 1; off >>= 1) s += __shfl_xor(s, off);
    const float mu = s * (1.f / 512.f);

    float sq = 0.f;
#pragma unroll
    for (int i = 0; i < 8; ++i) { float d = vals[i] - mu; sq += d * d; }
#pragma unroll
    for (int off = 32; off >= 1; off >>= 1) sq += __shfl_xor(sq, off);
    const float rs = rsqrtf(sq * (1.f / 512.f) + 1e-5f);

    const float* gp = g + lane * 8;
    const float* bp = b + lane * 8;
    float4 g0 = *(const float4*)gp, g1 = *(const float4*)(gp + 4);
    float4 b0 = *(const float4*)bp, b1 = *(const float4*)(bp + 4);
    float ga[8] = {g0.x, g0.y, g0.z, g0.w, g1.x, g1.y, g1.z, g1.w};
    float bb[8] = {b0.x, b0.y, b0.z, b0.w, b1.x, b1.y, b1.z, b1.w};

    u32 pk[4];
#pragma unroll
    for (int i = 0; i < 4; ++i) {
        float a0 = (vals[2 * i]     - mu) * rs * ga[2 * i]     + bb[2 * i];
        float a1 = (vals[2 * i + 1] - mu) * rs * ga[2 * i + 1] + bb[2 * i + 1];
        pk[i] = (u32)f2b(a0) | ((u32)f2b(a1) << 16);
    }
    *(uint4*)(Y + (size_t)row * 512 + lane * 8) = make_uint4(pk[0], pk[1], pk[2], pk[3]);
}

// ---------------------------------------------------------------------------
// Causal flash attention, in-block split-KV, FRAGMENT-NATIVE K/V loads.
// 1024 blocks x 256 thr (4 waves). Block = (bh, 32-row q-tile) via XCD
// swizzle + LPT. Wave w handles kv tiles {w, w+4, ...}; every K/V MFMA
// operand load is base + lane*16B (coalesced 1KB/instr) from Kf/Vf.
// Partial (m,l,O) merged via padded LDS after one __syncthreads.
// ---------------------------------------------------------------------------
__global__ __launch_bounds__(256, 4)
void k_attn(const u16* __restrict__ qkv, const u16* __restrict__ Kf,
            const u16* __restrict__ Vf, u16* __restrict__ y)
{
    __shared__ float Om[4][32 * 65];     // [wave][q*65 + d]
    __shared__ float Ml[4][32][2];       // [wave][q][{m,l}]
    const int tid = threadIdx.x;
    const int l = tid & 63, w = tid >> 6;
    const int l31 = l & 31, hi = l >> 5;
    const int bx = blockIdx.x;
    const int xcd = bx & 7, s = bx >> 3;
    const int bh = xcd * 2 + (s & 1);
    const int t_tile = 63 - (s >> 1);
    const int b = bh >> 3, hh = bh & 7;
    const int bT = b * TT, hh64 = hh * 64;

    const int qg = t_tile * 32 + l31;
    const int NT = (t_tile >> 1) + 1;    // kv tiles (64-wide) this q-tile needs

    f32x16 o[2] = {};
    float m = -1e30f, lsum = 0.f;

    if (w < NT) {
        // Q B-frags (scattered, but once per wave)
        s16x8 qf[4];
        {
            const u16* qsrc = qkv + (size_t)(bT + qg) * 1536 + hh64 + hi * 8;
#pragma unroll
            for (int dk = 0; dk < 4; ++dk) qf[dk] = *(const s16x8*)(qsrc + dk * 16);
        }
        const u16* kfb = Kf + ((size_t)bh * 8 + hi) * 2048 * 8;
        const u16* vfb = Vf + (((size_t)bh * 32) * 8 + hi) * 64 * 8;

        for (int g = w; g < NT; g += 4) {
            // K frags: coalesced 16B/lane
            s16x8 kf[8];
#pragma unroll
            for (int nb = 0; nb < 2; ++nb)
#pragma unroll
                for (int dk = 0; dk < 4; ++dk)
                    kf[nb * 4 + dk] = *(const s16x8*)(
                        kfb + ((size_t)(dk * 2) * 2048 + g * 64 + nb * 32 + l31) * 8);

            // S^T = K Q^T over d=64
            f32x16 sA[2];
#pragma unroll
            for (int nb = 0; nb < 2; ++nb) {
                f32x16 acc = {};
#pragma unroll
                for (int dk = 0; dk < 4; ++dk) acc = MFMA32(kf[nb * 4 + dk], qf[dk], acc);
                sA[nb] = acc;
            }

            // causal mask on the diagonal supertile
            if (g == NT - 1) {
                const int kvb = g * 64, hi4 = hi * 4;
#pragma unroll
                for (int nb = 0; nb < 2; ++nb)
#pragma unroll
                    for (int r = 0; r < 16; ++r) {
                        const int kv = kvb + nb * 32 + (r & 3) + 8 * (r >> 2) + hi4;
                        sA[nb][r] = (kv > qg) ? -1e30f : sA[nb][r];
                    }
            }

            // online softmax (scale 1/8 folded into exp)
            float tmp[16];
#pragma unroll
            for (int r = 0; r < 16; ++r) tmp[r] = fmaxf(sA[0][r], sA[1][r]);
#pragma unroll
            for (int st = 8; st >= 1; st >>= 1)
#pragma unroll
                for (int r = 0; r < 8; ++r)
                    if (r < st) tmp[r] = fmaxf(tmp[r], tmp[r + st]);
            float mt = fmaxf(tmp[0], __shfl_xor(tmp[0], 32));
            const float mn = fmaxf(m, mt);
            const float alpha = __expf((m - mn) * 0.125f);
            m = mn;
            const float mc = -mn * 0.125f;

            float p[2][16];
            float sum[16];
#pragma unroll
            for (int r = 0; r < 16; ++r) {
                p[0][r] = __expf(fmaf(sA[0][r], 0.125f, mc));
                p[1][r] = __expf(fmaf(sA[1][r], 0.125f, mc));
                sum[r] = p[0][r] + p[1][r];
            }
#pragma unroll
            for (int st = 8; st >= 1; st >>= 1)
#pragma unroll
                for (int r = 0; r < 8; ++r)
                    if (r < st) sum[r] += sum[r + st];
            float psum = sum[0] + __shfl_xor(sum[0], 32);
            lsum = lsum * alpha + psum;
#pragma unroll
            for (int dt = 0; dt < 2; ++dt)
#pragma unroll
                for (int r = 0; r < 16; ++r) o[dt][r] *= alpha;

            // P (f32, D-layout) -> bf16 A-frags via lane<->lane+32 exchange
            u32 pk2[2][8], sw2[2][8];
#pragma unroll
            for (int nb = 0; nb < 2; ++nb)
#pragma unroll
                for (int i = 0; i < 8; ++i) {
                    pk2[nb][i] = pkbf(p[nb][2 * i], p[nb][2 * i + 1]);
                    sw2[nb][i] = __shfl_xor(pk2[nb][i], 32);
                }
            s16x8 pa[4];
#pragma unroll
            for (int nb = 0; nb < 2; ++nb)
#pragma unroll
                for (int k16 = 0; k16 < 2; ++k16) {
                    const int i0 = k16 * 4;
                    u32 w0 = hi ? sw2[nb][i0 + 2] : pk2[nb][i0 + 0];
                    u32 w1 = hi ? sw2[nb][i0 + 3] : pk2[nb][i0 + 1];
                    u32 w2 = hi ? pk2[nb][i0 + 2] : sw2[nb][i0 + 0];
                    u32 w3 = hi ? pk2[nb][i0 + 3] : sw2[nb][i0 + 1];
                    u32x4 t4 = {w0, w1, w2, w3};
                    pa[nb * 2 + k16] = __builtin_bit_cast(s16x8, t4);
                }

            // O^T += V^T P^T, V frags coalesced 16B/lane
#pragma unroll
            for (int dt = 0; dt < 2; ++dt) {
                f32x16 acc = o[dt];
#pragma unroll
                for (int ks = 0; ks < 4; ++ks)
                    acc = MFMA32(*(const s16x8*)(
                        vfb + (((size_t)g * 8 + ks * 2) * 64 + dt * 32 + l31) * 8),
                        pa[ks], acc);
                o[dt] = acc;
            }
        }
    }

    // ---- dump partials: lane q = l31, d = dt*32 + (r&3)+8*(r>>2)+4*hi
#pragma unroll
    for (int dt = 0; dt < 2; ++dt)
#pragma unroll
        for (int r = 0; r < 16; ++r) {
            const int d = dt * 32 + (r & 3) + 8 * (r >> 2) + 4 * hi;
            Om[w][l31 * 65 + d] = o[dt][r];
        }
    Ml[w][l31][0] = m;
    Ml[w][l31][1] = lsum;
    __syncthreads();

    // ---- combine: thread -> (q = tid&31, d-range (tid>>5)*8 .. +7)
    const int q = tid & 31, d0 = (tid >> 5) * 8;
    float m0 = Ml[0][q][0], m1 = Ml[1][q][0], m2 = Ml[2][q][0], m3 = Ml[3][q][0];
    const float mstar = fmaxf(fmaxf(m0, m1), fmaxf(m2, m3));
    float sc[4];
    sc[0] = __expf((m0 - mstar) * 0.125f);
    sc[1] = __expf((m1 - mstar) * 0.125f);
    sc[2] = __expf((m2 - mstar) * 0.125f);
    sc[3] = __expf((m3 - mstar) * 0.125f);
    const float lstar = sc[0] * Ml[0][q][1] + sc[1] * Ml[1][q][1]
                      + sc[2] * Ml[2][q][1] + sc[3] * Ml[3][q][1];
    float ov[8];
#pragma unroll
    for (int j = 0; j < 8; ++j) ov[j] = 0.f;
#pragma unroll
    for (int ww = 0; ww < 4; ++ww) {
        const float scw = sc[ww];
        const float* src = &Om[ww][q * 65 + d0];
#pragma unroll
        for (int j = 0; j < 8; ++j) ov[j] = fmaf(scw, src[j], ov[j]);
    }
    const float inv = 1.f / lstar;
    u32 pk[4];
#pragma unroll
    for (int i = 0; i < 4; ++i) pk[i] = pkbf(ov[2 * i] * inv, ov[2 * i + 1] * inv);
    u16* yp = y + (size_t)(bT + t_tile * 32 + q) * 512 + hh64 + d0;
    *(uint4*)yp = make_uint4(pk[0], pk[1], pk[2], pk[3]);
}

// ---------------------------------------------------------------------------
// K/V -> fragment-native layouts (one LDS-tiled pass).
// Kf[bh][c][t][8]  = K[t][c*8+j]   (c = 8-elem d-chunk)
// Vf[bh][g][cc][d][8] = V[g*64+cc*8+j][d]
// 512 blocks (16 bh x 32 kv-tiles of 64), 256 threads.
// ---------------------------------------------------------------------------
__global__ __launch_bounds__(256)
void k_kvf(const u16* __restrict__ big, u16* __restrict__ Kf, u16* __restrict__ Vf)
{
    __shared__ u16 TK[64][66];
    __shared__ u16 TV[64][66];
    const int tid = threadIdx.x;
    const int bh = blockIdx.x >> 5, g = blockIdx.x & 31;
    const int b = bh >> 3, hh = bh & 7;

    // phase 1: coalesced read of K,V tiles (64 t x 64 d)
#pragma unroll
    for (int i = 0; i < 2; ++i) {
        const int u = i * 256 + tid;
        const int r = u >> 3, c = u & 7;
        const u16* src = big + (size_t)(b * TT + g * 64 + r) * 1536 + 512 + hh * 64 + c * 8;
        s16x8 kv0 = *(const s16x8*)src;
        s16x8 vv0 = *(const s16x8*)(src + 512);
        u32x4 ka = __builtin_bit_cast(u32x4, kv0);
        u32x4 va = __builtin_bit_cast(u32x4, vv0);
        u32* dk_ = (u32*)&TK[r][c * 8];
        dk_[0] = ka[0]; dk_[1] = ka[1]; dk_[2] = ka[2]; dk_[3] = ka[3];
        u32* dv_ = (u32*)&TV[r][c * 8];
        dv_[0] = va[0]; dv_[1] = va[1]; dv_[2] = va[2]; dv_[3] = va[3];
    }
    __syncthreads();

    // phase 2a: Kf[c][t][8] = row segments of TK (coalesced writes)
#pragma unroll
    for (int i = 0; i < 2; ++i) {
        const int u = i * 256 + tid;
        const int c2 = u >> 6, t = u & 63;
        const u32* s4 = (const u32*)&TK[t][c2 * 8];
        *(uint4*)(Kf + (((size_t)bh * 8 + c2) * 2048 + g * 64 + t) * 8)
            = make_uint4(s4[0], s4[1], s4[2], s4[3]);
    }
    // phase 2b: Vf[g][cc][d][8] = columns of TV (2-way-bank scalar reads)
#pragma unroll
    for (int i = 0; i < 2; ++i) {
        const int u = i * 256 + tid;
        const int cc = u >> 6, d = u & 63;
        u32 pk[4];
#pragma unroll
        for (int jp = 0; jp < 4; ++jp)
            pk[jp] = (u32)TV[cc * 8 + 2 * jp][d] | ((u32)TV[cc * 8 + 2 * jp + 1][d] << 16);
        *(uint4*)(Vf + ((((size_t)bh * 32 + g) * 8 + cc) * 64 + d) * 8)
            = make_uint4(pk[0], pk[1], pk[2], pk[3]);
    }
}

// ---------------------------------------------------------------------------
// Fast LDS-tiled weight transpose fp32[K][N] -> bf16[N][K], 64x64 tiles.
// ---------------------------------------------------------------------------
__global__ __launch_bounds__(256)
void k_wt_fast(const float* __restrict__ Wqkv, const float* __restrict__ Wo,
               const float* __restrict__ Wf1, const float* __restrict__ Wf2,
               const float* __restrict__ Win, const float* __restrict__ Wout,
               u16* __restrict__ WqkvT, u16* __restrict__ WoT,
               u16* __restrict__ Wf1T, u16* __restrict__ Wf2T,
               u16* __restrict__ WinT, u16* __restrict__ WoutT)
{
    __shared__ float T[64][65];
    const int tid = threadIdx.x;
    int id = blockIdx.x;
    const float* W; u16* Wt; int K, N;
    if (id < 192)      { W = Wqkv; Wt = WqkvT; K = 512;  N = 1536; }
    else if (id < 256) { W = Wo;   Wt = WoT;   K = 512;  N = 512;  id -= 192; }
    else if (id < 512) { W = Wf1;  Wt = Wf1T;  K = 512;  N = 2048; id -= 256; }
    else if (id < 768) { W = Wf2;  Wt = Wf2T;  K = 2048; N = 512;  id -= 512; }
    else if (id < 784) { W = Win;  Wt = WinT;  K = 128;  N = 512;  id -= 768; }
    else               { W = Wout; Wt = WoutT; K = 512;  N = 128;  id -= 784; }
    const int nt = N >> 6;
    const int ktile = id / nt, ntile = id - ktile * nt;
    const int kb = ktile * 64, nb = ntile * 64;
#pragma unroll
    for (int i = 0; i < 4; ++i) {
        const int r = i * 16 + (tid >> 4), c = (tid & 15) * 4;
        const float4 v = *(const float4*)&W[(size_t)(kb + r) * N + nb + c];
        T[r][c] = v.x; T[r][c + 1] = v.y; T[r][c + 2] = v.z; T[r][c + 3] = v.w;
    }
    __syncthreads();
    const int n = tid >> 2, k0 = (tid & 3) * 16;
    u32 pk[8];
#pragma unroll
    for (int i = 0; i < 8; ++i)
        pk[i] = pkbf(T[k0 + 2 * i][n], T[k0 + 2 * i + 1][n]);
    uint4* dst = (uint4*)(Wt + (size_t)(nb + n) * K + kb + k0);
    dst[0] = make_uint4(pk[0], pk[1], pk[2], pk[3]);
    dst[1] = make_uint4(pk[4], pk[5], pk[6], pk[7]);
}

// x fp32 -> bf16 (8 elems/thread)
__global__ __launch_bounds__(256)
void k_f2b(const float* __restrict__ x, u16* __restrict__ xb)
{
    const int g = blockIdx.x * 256 + threadIdx.x;
    const float4* s = (const float4*)(x + (size_t)g * 8);
    float4 a = s[0], c = s[1];
    u32 pk[4] = {
        (u32)f2b(a.x) | ((u32)f2b(a.y) << 16), (u32)f2b(a.z) | ((u32)f2b(a.w) << 16),
        (u32)f2b(c.x) | ((u32)f2b(c.y) << 16), (u32)f2b(c.z) | ((u32)f2b(c.w) << 16)};
    *(uint4*)(xb + (size_t)g * 8) = make_uint4(pk[0], pk[1], pk[2], pk[3]);
}

// ---------------------------------------------------------------------------
extern "C" void kernel_launch(void* const* d_in, const int* in_sizes, int n_in,
                              void* d_out, int out_size, void* d_ws, size_t ws_size,
                              hipStream_t stream)
{
    const float* x    = (const float*)d_in[0];
    const float* Win  = (const float*)d_in[1];
    const float* bin_ = (const float*)d_in[2];
    const float* Wqkv = (const float*)d_in[3];
    const float* bqkv = (const float*)d_in[4];
    const float* Wo   = (const float*)d_in[5];
    const float* bo   = (const float*)d_in[6];
    const float* ln1g = (const float*)d_in[7];
    const float* ln1b = (const float*)d_in[8];
    const float* Wf1  = (const float*)d_in[9];
    const float* bf1  = (const float*)d_in[10];
    const float* Wf2  = (const float*)d_in[11];
    const float* bf2  = (const float*)d_in[12];
    const float* ln2g = (const float*)d_in[13];
    const float* ln2b = (const float*)d_in[14];
    const float* lnfg = (const float*)d_in[15];
    const float* lnfb = (const float*)d_in[16];
    const float* Wout = (const float*)d_in[17];
    const float* bout = (const float*)d_in[18];
    float* out = (float*)d_out;

    const int M = 4096;
    char* ws = (char*)d_ws;
    float* h    = (float*)(ws + 0);                 //  8 MB  fp32 residual
    u16*   y    = (u16*)(ws + 8388608);             //  4 MB  bf16 LN/attn out
    u16*   big  = (u16*)(ws + 12582912);            // 16 MB  bf16 qkv/ff1
    u16*   Kf   = (u16*)(ws + 29360128);            //  4 MB  K frag-native
    u16*   Vf   = (u16*)(ws + 33554432);            //  4 MB  V frag-native
    u16*   xb   = big;                              //  aliased: only used pre-layer0
    u16*   WinT  = (u16*)(ws + 37748736);
    u16*   WoutT = (u16*)(ws + 37879808);
    u16*   WqkvT = (u16*)(ws + 38010880);
    u16*   WoT   = (u16*)(ws + 39583744);
    u16*   Wf1T  = (u16*)(ws + 40108032);
    u16*   Wf2T  = (u16*)(ws + 42205184);

    dim3 blk(256);

    k_f2b<<<256, blk, 0, stream>>>(x, xb);

    for (int lyr = 0; lyr < 4; ++lyr) {
        k_wt_fast<<<(lyr == 0) ? 800 : 768, blk, 0, stream>>>(
            Wqkv + (size_t)lyr * 512 * 1536, Wo + (size_t)lyr * 512 * 512,
            Wf1 + (size_t)lyr * 512 * 2048, Wf2 + (size_t)lyr * 2048 * 512,
            Win, Wout, WqkvT, WoT, Wf1T, Wf2T, WinT, WoutT);
        if (lyr == 0) {
            // input projection + sinusoidal PE -> h (fp32); xb aliases big
            k_gemm_mfma<EPI_PE, 64, 64><<<dim3(8, 64), blk, 0, stream>>>(
                xb, WinT, bin_, nullptr, h, M, 512, 128);
        }
        k_ln<<<1024, blk, 0, stream>>>(h, ln1g + lyr * 512, ln1b + lyr * 512, y);
        k_gemm_mfma<EPI_BF16, 64, 128><<<dim3(12, 64), blk, 0, stream>>>(
            y, WqkvT, bqkv + lyr * 1536, nullptr, big, M, 1536, 512);
        k_kvf<<<512, blk, 0, stream>>>(big, Kf, Vf);
        k_attn<<<1024, blk, 0, stream>>>(big, Kf, Vf, y);
        k_gemm_mfma<EPI_RES, 64, 64><<<dim3(8, 64), blk, 0, stream>>>(
            y, WoT, bo + lyr * 512, h, h, M, 512, 512);
        k_ln<<<1024, blk, 0, stream>>>(h, ln2g + lyr * 512, ln2b + lyr * 512, y);
        k_gemm_mfma<EPI_GELU, 64, 128><<<dim3(16, 64), blk, 0, stream>>>(
            y, Wf1T, bf1 + lyr * 2048, nullptr, big, M, 2048, 512);
        k_gemm_mfma<EPI_RES, 64, 64><<<dim3(8, 64), blk, 0, stream>>>(
            big, Wf2T, bf2 + lyr * 512, h, h, M, 512, 2048);
    }

    k_ln<<<1024, blk, 0, stream>>>(h, lnfg, lnfb, y);
    k_gemm_mfma<EPI_OUTF, 64, 64><<<dim3(2, 64), blk, 0, stream>>>(
        y, WoutT, bout, nullptr, out, M, 128, 512);
}